// Round 7
// baseline (723.622 us; speedup 1.0000x reference)
//
#include <hip/hip_runtime.h>
#include <hip/hip_bf16.h>
#include <math.h>

#define DI __device__ __forceinline__

typedef __bf16 bf16x8 __attribute__((ext_vector_type(8)));
typedef float f32x4 __attribute__((ext_vector_type(4)));
typedef short s16x8 __attribute__((ext_vector_type(8)));

// ---------- helpers ----------
DI unsigned short f2bf(float f) {
  unsigned int u = __builtin_bit_cast(unsigned int, f);
  unsigned int r = (u + 0x7fffu + ((u >> 16) & 1u)) >> 16;
  return (unsigned short)r;
}
DI float bf2f(unsigned short h) {
  unsigned int u = ((unsigned int)h) << 16;
  return __builtin_bit_cast(float, u);
}

DI void gload16(const void* g, void* l) {
  __builtin_amdgcn_global_load_lds(
      (const __attribute__((address_space(1))) void*)g,
      (__attribute__((address_space(3))) void*)l, 16, 0, 0);
}

DI unsigned ldsoff(const void* p) {
  return (unsigned)(size_t)(const __attribute__((address_space(3))) void*)p;
}

// asm ds_read_b128 with compile-time offset: compiler cannot sink/elide it.
template <int OFF>
DI bf16x8 ds128(unsigned base) {
  bf16x8 r;
  asm volatile("ds_read_b128 %0, %1 offset:%2" : "=v"(r) : "v"(base), "i"(OFF));
  return r;
}
// counted waits + sched_barrier(0) (MFMA intrinsics can hoist past bare
// inline-asm waitcnt; the sched_barrier pins them below).
template <int N>
DI void lgkm() {
  asm volatile("s_waitcnt lgkmcnt(%0)" ::"i"(N));
  __builtin_amdgcn_sched_barrier(0);
}
template <int N>
DI void vmc() {
  asm volatile("s_waitcnt vmcnt(%0)" ::"i"(N));
  __builtin_amdgcn_sched_barrier(0);
}

// 2-D XCD rasterization for GEMMs.
DI void xcd_map(int BN, int& m0, int& n0) {
  const int nx = gridDim.x;
  int orig = blockIdx.y * nx + blockIdx.x;
  int xcd = orig & 7, k = orig >> 3;
  int xm = xcd >> 2, xn = xcd & 3;
  int nband = nx >> 2;
  m0 = (xm * 8 + (k & 7)) * 256;
  n0 = (xn * nband + (k >> 3)) * BN;
}

// ---------- transpose + fp32->bf16 cast ----------
__global__ __launch_bounds__(256)
void transpose_cast_f32(const float* __restrict__ in, unsigned short* __restrict__ out,
                        int R, int C) {
  __shared__ unsigned int t[64 * 65];
  const int r0 = blockIdx.y * 64, c0 = blockIdx.x * 64;
  const int tid = threadIdx.x;
#pragma unroll
  for (int p = 0; p < 4; ++p) {
    int e = p * 1024 + tid * 4;
    int r = e >> 6, c = e & 63;
    float4 v = *(const float4*)(in + (size_t)(r0 + r) * C + c0 + c);
    t[r * 65 + c + 0] = f2bf(v.x);
    t[r * 65 + c + 1] = f2bf(v.y);
    t[r * 65 + c + 2] = f2bf(v.z);
    t[r * 65 + c + 3] = f2bf(v.w);
  }
  __syncthreads();
  const int oc = tid >> 2, ch = tid & 3;
  alignas(16) unsigned short vals[16];
#pragma unroll
  for (int j = 0; j < 16; ++j) vals[j] = (unsigned short)t[(ch * 16 + j) * 65 + oc];
  size_t ob = (size_t)(c0 + oc) * R + r0 + ch * 16;
  *(s16x8*)(out + ob) = *(const s16x8*)(vals);
  *(s16x8*)(out + ob + 8) = *(const s16x8*)(vals + 8);
}

// ---------- V transpose ----------
__global__ __launch_bounds__(256)
void transpose_v(const unsigned short* __restrict__ qkv, unsigned short* __restrict__ vT) {
  __shared__ unsigned int t[64 * 65];
  const int s0 = blockIdx.x * 64, d0 = blockIdx.y * 64, bh = blockIdx.z;
  const int b = bh >> 4, h = bh & 15;
  const int tid = threadIdx.x;
#pragma unroll
  for (int p = 0; p < 2; ++p) {
    int id = p * 256 + tid;
    int r = id >> 3, c = (id & 7) * 8;
    s16x8 v = *(const s16x8*)(qkv + (size_t)(b * 2048 + s0 + r) * 6144 + 4096 + h * 128 + d0 + c);
#pragma unroll
    for (int j = 0; j < 8; ++j) t[r * 65 + c + j] = (unsigned short)((const unsigned short*)&v)[j];
  }
  __syncthreads();
  const int oc = tid >> 2, ch = tid & 3;
  alignas(16) unsigned short vals[16];
#pragma unroll
  for (int j = 0; j < 16; ++j) vals[j] = (unsigned short)t[(ch * 16 + j) * 65 + oc];
  size_t ob = (size_t)(bh * 128 + d0 + oc) * 2048 + s0 + ch * 16;
  *(s16x8*)(vT + ob) = *(const s16x8*)(vals);
  *(s16x8*)(vT + ob + 8) = *(const s16x8*)(vals + 8);
}

// ---------- LayerNorm fp32 -> bf16, row = 2048 ----------
__global__ __launch_bounds__(256)
void ln_kernel(const float* __restrict__ x, const float* __restrict__ g,
               const float* __restrict__ bi, unsigned short* __restrict__ y) {
  __shared__ float red[8];
  const int row = blockIdx.x, tid = threadIdx.x;
  const float* xp = x + (size_t)row * 2048 + tid * 8;
  float4 v0 = *(const float4*)xp;
  float4 v1 = *(const float4*)(xp + 4);
  float v[8] = {v0.x, v0.y, v0.z, v0.w, v1.x, v1.y, v1.z, v1.w};
  float s = 0.f;
#pragma unroll
  for (int j = 0; j < 8; ++j) s += v[j];
#pragma unroll
  for (int d = 1; d < 64; d <<= 1) s += __shfl_xor(s, d);
  if ((tid & 63) == 0) red[tid >> 6] = s;
  __syncthreads();
  float mean = (red[0] + red[1] + red[2] + red[3]) * (1.f / 2048.f);
  float dd[8], sq = 0.f;
#pragma unroll
  for (int j = 0; j < 8; ++j) { dd[j] = v[j] - mean; sq += dd[j] * dd[j]; }
#pragma unroll
  for (int d = 1; d < 64; d <<= 1) sq += __shfl_xor(sq, d);
  if ((tid & 63) == 0) red[4 + (tid >> 6)] = sq;
  __syncthreads();
  float var = (red[4] + red[5] + red[6] + red[7]) * (1.f / 2048.f);
  float rs = rsqrtf(var + 1e-5f);
  float4 g0 = *(const float4*)(g + tid * 8), g1 = *(const float4*)(g + tid * 8 + 4);
  float4 b0 = *(const float4*)(bi + tid * 8), b1 = *(const float4*)(bi + tid * 8 + 4);
  float gg[8] = {g0.x, g0.y, g0.z, g0.w, g1.x, g1.y, g1.z, g1.w};
  float bb[8] = {b0.x, b0.y, b0.z, b0.w, b1.x, b1.y, b1.z, b1.w};
  alignas(16) unsigned short o[8];
#pragma unroll
  for (int j = 0; j < 8; ++j) o[j] = f2bf(dd[j] * rs * gg[j] + bb[j]);
  *(s16x8*)(y + (size_t)row * 2048 + tid * 8) = *(const s16x8*)o;
}

// ---------- shared GEMM staging ----------
DI void stage_half(const unsigned short* __restrict__ G, int ld, int rbase, int kt,
                   int h, unsigned short* dst, int tid) {
#pragma unroll
  for (int i = 0; i < 2; ++i) {
    int id = i * 512 + tid;
    int rl = id >> 3, sl = id & 7;
    int ss = sl ^ (rl & 7);
    gload16(G + (size_t)(rbase + h * 128 + rl) * ld + kt + ss * 8,
            (char*)dst + h * 16384 + id * 16);
  }
}

#define RDA(dst, B0_, B1_, OFS)                                        \
  dst[0][0] = ds128<(OFS) + 0>(B0_);    dst[0][1] = ds128<(OFS) + 0>(B1_);    \
  dst[1][0] = ds128<(OFS) + 2048>(B0_); dst[1][1] = ds128<(OFS) + 2048>(B1_); \
  dst[2][0] = ds128<(OFS) + 4096>(B0_); dst[2][1] = ds128<(OFS) + 4096>(B1_); \
  dst[3][0] = ds128<(OFS) + 6144>(B0_); dst[3][1] = ds128<(OFS) + 6144>(B1_);

#define RDB(dst, B0_, B1_, OFS)                                        \
  dst[0][0] = ds128<(OFS) + 0>(B0_);    dst[0][1] = ds128<(OFS) + 0>(B1_);    \
  dst[1][0] = ds128<(OFS) + 2048>(B0_); dst[1][1] = ds128<(OFS) + 2048>(B1_);

// ---------- 256x256 GEMM (QKV): counted-asm pipelined, 4 clusters/K-tile ----
// (r4-verified version: b23 drains under Q1, a1 under Q2; vmcnt(6) ledger.
// The r5 pure-phase variant measured ~5us slower at the total level.)
// MODE 0: out bf16 = acc + bias ; MODE 1: out f32 = acc + bias + res
template <int MODE>
__global__ __launch_bounds__(512, 2)
void gemm256(const unsigned short* __restrict__ A, int lda,
             const unsigned short* __restrict__ B,
             const float* __restrict__ bias,
             const void* __restrict__ resg,
             void* __restrict__ out, int ldc, int K) {
  __shared__ alignas(16) unsigned short As[2][256 * 64];
  __shared__ alignas(16) unsigned short Bs[2][256 * 64];

  const int tid = threadIdx.x;
  const int l = tid & 63, w = tid >> 6;
  const int wr = w >> 2, wc = w & 3;
  const int lr = l & 15, lg = l >> 4;

  int m0, n0;
  xcd_map(256, m0, n0);

  const int NT = K >> 6;

  f32x4 acc[8][4];
  const f32x4 z4 = {0.f, 0.f, 0.f, 0.f};
#pragma unroll
  for (int i = 0; i < 8; ++i)
#pragma unroll
    for (int j = 0; j < 4; ++j) acc[i][j] = z4;

  const int s7 = lr & 7;
  const unsigned swz0 = (unsigned)((lg ^ s7) << 4);
  const unsigned swz1 = (unsigned)(((4 | lg) ^ s7) << 4);
  const unsigned rA = (unsigned)((wr * 128 + lr) * 128);
  const unsigned rB = (unsigned)((wc * 64 + lr) * 128);
  const unsigned aA0 = ldsoff(&As[0][0]) + rA + swz0;
  const unsigned aA1 = ldsoff(&As[0][0]) + rA + swz1;
  const unsigned bA0 = ldsoff(&Bs[0][0]) + rB + swz0;
  const unsigned bA1 = ldsoff(&Bs[0][0]) + rB + swz1;

  stage_half(A, lda, m0, 0, 0, As[0], tid);
  stage_half(A, lda, m0, 0, 1, As[0], tid);
  stage_half(B, K, n0, 0, 0, Bs[0], tid);
  stage_half(B, K, n0, 0, 1, Bs[0], tid);
  if (NT > 1) {
    stage_half(B, K, n0, 64, 0, Bs[1], tid);
    stage_half(B, K, n0, 64, 1, Bs[1], tid);
    stage_half(A, lda, m0, 64, 0, As[1], tid);
    asm volatile("s_waitcnt vmcnt(6)" ::: "memory");
  } else {
    asm volatile("s_waitcnt vmcnt(0)" ::: "memory");
  }
  __builtin_amdgcn_s_barrier();

  for (int t = 0; t < NT; ++t) {
    const unsigned co = (unsigned)((t & 1) * 32768);
    const unsigned a0b = aA0 + co, a1b = aA1 + co;
    const unsigned b0b = bA0 + co, b1b = bA1 + co;
    bf16x8 a0[4][2], a1[4][2], bfr[4][2];

    // ---- c1: issue a0(8)+b01(4); stage Ah1(t+1); issue b23(4); lgkm<4>;
    //      Q1 = a0 x b01 (b23 drains underneath) ----
#pragma unroll
    for (int i = 0; i < 4; ++i) {
      a0[i][0] = ds128<0>(a0b + i * 2048);
      a0[i][1] = ds128<0>(a1b + i * 2048);
    }
#pragma unroll
    for (int j = 0; j < 2; ++j) {
      bfr[j][0] = ds128<0>(b0b + j * 2048);
      bfr[j][1] = ds128<0>(b1b + j * 2048);
    }
    if (t + 1 < NT) stage_half(A, lda, m0, (t + 1) * 64, 1, As[(t & 1) ^ 1], tid);
#pragma unroll
    for (int j = 2; j < 4; ++j) {
      bfr[j][0] = ds128<0>(b0b + j * 2048);
      bfr[j][1] = ds128<0>(b1b + j * 2048);
    }
    lgkm<4>();
    __builtin_amdgcn_s_setprio(1);
#pragma unroll
    for (int i = 0; i < 4; ++i)
#pragma unroll
      for (int j = 0; j < 2; ++j)
#pragma unroll
        for (int kk = 0; kk < 2; ++kk)
          acc[i][j] = __builtin_amdgcn_mfma_f32_16x16x32_bf16(a0[i][kk], bfr[j][kk], acc[i][j], 0, 0, 0);
    __builtin_amdgcn_s_setprio(0);
    __builtin_amdgcn_s_barrier();

    // ---- c2: issue a1(8); lgkm<8> (drains b23); Q2 = a0 x b23 ----
#pragma unroll
    for (int i = 0; i < 4; ++i) {
      a1[i][0] = ds128<8192>(a0b + i * 2048);
      a1[i][1] = ds128<8192>(a1b + i * 2048);
    }
    lgkm<8>();
    __builtin_amdgcn_s_setprio(1);
#pragma unroll
    for (int i = 0; i < 4; ++i)
#pragma unroll
      for (int j = 2; j < 4; ++j)
#pragma unroll
        for (int kk = 0; kk < 2; ++kk)
          acc[i][j] = __builtin_amdgcn_mfma_f32_16x16x32_bf16(a0[i][kk], bfr[j][kk], acc[i][j], 0, 0, 0);
    __builtin_amdgcn_s_setprio(0);
    __builtin_amdgcn_s_barrier();

    // ---- c3: stage Bh0(t+2); lgkm<0> (drains a1); Q3 = a1 x b01 ----
    if (t + 2 < NT) stage_half(B, K, n0, (t + 2) * 64, 0, Bs[t & 1], tid);
    lgkm<0>();
    __builtin_amdgcn_s_setprio(1);
#pragma unroll
    for (int i = 0; i < 4; ++i)
#pragma unroll
      for (int j = 0; j < 2; ++j)
#pragma unroll
        for (int kk = 0; kk < 2; ++kk)
          acc[i + 4][j] = __builtin_amdgcn_mfma_f32_16x16x32_bf16(a1[i][kk], bfr[j][kk], acc[i + 4][j], 0, 0, 0);
    __builtin_amdgcn_s_setprio(0);
    __builtin_amdgcn_s_barrier();

    // ---- c4: stage Bh1(t+2)+Ah0(t+2); Q4 = a1 x b23; vmc ----
    if (t + 2 < NT) {
      stage_half(B, K, n0, (t + 2) * 64, 1, Bs[t & 1], tid);
      stage_half(A, lda, m0, (t + 2) * 64, 0, As[t & 1], tid);
    }
    __builtin_amdgcn_s_setprio(1);
#pragma unroll
    for (int i = 0; i < 4; ++i)
#pragma unroll
      for (int j = 2; j < 4; ++j)
#pragma unroll
        for (int kk = 0; kk < 2; ++kk)
          acc[i + 4][j] = __builtin_amdgcn_mfma_f32_16x16x32_bf16(a1[i][kk], bfr[j][kk], acc[i + 4][j], 0, 0, 0);
    __builtin_amdgcn_s_setprio(0);
    if (t + 2 < NT) { vmc<6>(); } else { vmc<0>(); }
    __builtin_amdgcn_s_barrier();
  }

#pragma unroll
  for (int i = 0; i < 8; ++i) {
    int r0 = m0 + wr * 128 + i * 16 + lg * 4;
#pragma unroll
    for (int j = 0; j < 4; ++j) {
      int col = n0 + wc * 64 + j * 16 + lr;
      float bb = bias[col];
#pragma unroll
      for (int q = 0; q < 4; ++q) {
        size_t off = (size_t)(r0 + q) * ldc + col;
        float v = acc[i][j][q] + bb;
        if (MODE == 0) {
          ((unsigned short*)out)[off] = f2bf(v);
        } else {
          ((float*)out)[off] = v + ((const float*)resg)[off];
        }
      }
    }
  }
}

// ---------- 256x128 GEMM single-B (O-proj / proj): counted-asm 2-cluster ----
template <int MODE, bool DUAL>
__global__ __launch_bounds__(512, 2)
void gemm_n128(const unsigned short* __restrict__ A, int lda,
               const unsigned short* __restrict__ B0,
               const unsigned short* __restrict__ B1,
               const float* __restrict__ bias0, const float* __restrict__ bias1,
               const void* __restrict__ resg,
               void* __restrict__ out, int ldc, int K) {
  __shared__ alignas(16) unsigned short As[2][256 * 64];
  __shared__ alignas(16) unsigned short Bs0[2][128 * 64];

  const int tid = threadIdx.x;
  const int l = tid & 63, w = tid >> 6;
  const int wr = w >> 2, wc = w & 3;
  const int lr = l & 15, lg = l >> 4;

  int m0, n0;
  xcd_map(128, m0, n0);

  const int NT = K >> 6;

  f32x4 acc0[8][2];
  const f32x4 z4 = {0.f, 0.f, 0.f, 0.f};
#pragma unroll
  for (int i = 0; i < 8; ++i)
#pragma unroll
    for (int j = 0; j < 2; ++j) acc0[i][j] = z4;

  const int s7 = lr & 7;
  const unsigned swz0 = (unsigned)((lg ^ s7) << 4);
  const unsigned swz1 = (unsigned)(((4 | lg) ^ s7) << 4);
  const unsigned rA = (unsigned)((wr * 128 + lr) * 128);
  const unsigned rB = (unsigned)((wc * 32 + lr) * 128);
  const unsigned aA0 = ldsoff(&As[0][0]) + rA + swz0;
  const unsigned aA1 = ldsoff(&As[0][0]) + rA + swz1;
  const unsigned bA0 = ldsoff(&Bs0[0][0]) + rB + swz0;
  const unsigned bA1 = ldsoff(&Bs0[0][0]) + rB + swz1;

  // prologue
  stage_half(A, lda, m0, 0, 0, As[0], tid);
  stage_half(A, lda, m0, 0, 1, As[0], tid);
  stage_half(B0, K, n0, 0, 0, Bs0[0], tid);
  if (NT > 1) {
    stage_half(B0, K, n0, 64, 0, Bs0[1], tid);
    stage_half(A, lda, m0, 64, 0, As[1], tid);
    asm volatile("s_waitcnt vmcnt(4)" ::: "memory");
  } else {
    asm volatile("s_waitcnt vmcnt(0)" ::: "memory");
  }
  __builtin_amdgcn_s_barrier();

  for (int t = 0; t < NT; ++t) {
    const int cur = t & 1;
    const unsigned ca = aA0 + (unsigned)(cur * 32768);
    const unsigned ca1 = aA1 + (unsigned)(cur * 32768);
    const unsigned cb = bA0 + (unsigned)(cur * 16384);
    const unsigned cb1 = bA1 + (unsigned)(cur * 16384);
    bf16x8 a0[4][2], a1[4][2], b0f[2][2];

    // ---- c1: issue a0(8)+b0(4); stage Ah1(t+1); issue a1(8); lgkm<8>;
    //      Q1 = a0 x b0 (a1 drains underneath) ----
#pragma unroll
    for (int i = 0; i < 4; ++i) {
      a0[i][0] = ds128<0>(ca + i * 2048);
      a0[i][1] = ds128<0>(ca1 + i * 2048);
    }
#pragma unroll
    for (int j = 0; j < 2; ++j) {
      b0f[j][0] = ds128<0>(cb + j * 2048);
      b0f[j][1] = ds128<0>(cb1 + j * 2048);
    }
    if (t + 1 < NT) stage_half(A, lda, m0, (t + 1) * 64, 1, As[cur ^ 1], tid);
#pragma unroll
    for (int i = 0; i < 4; ++i) {
      a1[i][0] = ds128<8192>(ca + i * 2048);
      a1[i][1] = ds128<8192>(ca1 + i * 2048);
    }
    lgkm<8>();
    __builtin_amdgcn_s_setprio(1);
#pragma unroll
    for (int i = 0; i < 4; ++i)
#pragma unroll
      for (int j = 0; j < 2; ++j)
#pragma unroll
        for (int kk = 0; kk < 2; ++kk)
          acc0[i][j] = __builtin_amdgcn_mfma_f32_16x16x32_bf16(a0[i][kk], b0f[j][kk], acc0[i][j], 0, 0, 0);
    __builtin_amdgcn_s_setprio(0);
    __builtin_amdgcn_s_barrier();

    // ---- c2: stage B0(t+2); lgkm<0> (drain a1); stage Ah0(t+2); Q2 ----
    if (t + 2 < NT) stage_half(B0, K, n0, (t + 2) * 64, 0, Bs0[cur], tid);
    lgkm<0>();
    if (t + 2 < NT) stage_half(A, lda, m0, (t + 2) * 64, 0, As[cur], tid);
    __builtin_amdgcn_s_setprio(1);
#pragma unroll
    for (int i = 0; i < 4; ++i)
#pragma unroll
      for (int j = 0; j < 2; ++j)
#pragma unroll
        for (int kk = 0; kk < 2; ++kk)
          acc0[i + 4][j] = __builtin_amdgcn_mfma_f32_16x16x32_bf16(a1[i][kk], b0f[j][kk], acc0[i + 4][j], 0, 0, 0);
    __builtin_amdgcn_s_setprio(0);
    if (t + 2 < NT) { vmc<4>(); } else { vmc<0>(); }
    __builtin_amdgcn_s_barrier();
  }

  // epilogue
#pragma unroll
  for (int i = 0; i < 8; ++i) {
    int r0 = m0 + wr * 128 + i * 16 + lg * 4;
#pragma unroll
    for (int j = 0; j < 2; ++j) {
      int col = n0 + wc * 32 + j * 16 + lr;
      float bb0 = bias0[col];
#pragma unroll
      for (int q = 0; q < 4; ++q) {
        size_t off = (size_t)(r0 + q) * ldc + col;
        float v = acc0[i][j][q] + bb0;
        ((float*)out)[off] = v + ((const float*)resg)[off];
      }
    }
  }
}

// ---------- MLP dual GEMM: 256x128, counted-wait asm-pipelined 4-phase ------
// (r2/r4-verified schedule)
DI void mmq(f32x4 (&acc)[8][2], int io, const bf16x8 (&af)[4][2], const bf16x8 (&bf)[2][2]) {
#pragma unroll
  for (int kk = 0; kk < 2; ++kk)
#pragma unroll
    for (int i = 0; i < 4; ++i)
#pragma unroll
      for (int j = 0; j < 2; ++j)
        acc[io + i][j] = __builtin_amdgcn_mfma_f32_16x16x32_bf16(af[i][kk], bf[j][kk], acc[io + i][j], 0, 0, 0);
}

#define MLP_ITER(t, CUR, A0C, B0C, B1C, A1C, A0N, B0N)                         \
  {                                                                            \
    /* P1: issue b1(t); wait a0(t),b0(t); Q1 = a0 x b0 -> acc0 lo */           \
    RDB(B1C, cA0, cA1, (CUR) * 16384);                                         \
    lgkm<4>();                                                                 \
    __builtin_amdgcn_s_setprio(1);                                             \
    mmq(acc0, 0, A0C, B0C);                                                    \
    __builtin_amdgcn_s_setprio(0);                                             \
    __builtin_amdgcn_sched_barrier(0);                                         \
    __builtin_amdgcn_s_barrier();                                              \
    /* P2: stage B0(t+2); issue a1(t); wait b1(t); Q2 = a0 x b1 -> acc1 lo */  \
    if ((t) + 2 < NT) stage_half(B0, K, n0, ((t) + 2) * 64, 0, Bs0[CUR], tid); \
    RDA(A1C, aA0, aA1, (CUR) * 32768 + 8192);                                  \
    lgkm<8>();                                                                 \
    __builtin_amdgcn_s_setprio(1);                                             \
    mmq(acc1, 0, A0C, B1C);                                                    \
    __builtin_amdgcn_s_setprio(0);                                             \
    if ((t) + 2 < NT) { vmc<2>(); } else { vmc<0>(); }                         \
    __builtin_amdgcn_s_barrier();                                              \
    /* P3: stage B1(t+2); issue a0(t+1); wait a1(t); Q3 = a1 x b0 -> acc0 hi */\
    if ((t) + 2 < NT) stage_half(B1, K, n0, ((t) + 2) * 64, 0, Bs1[CUR], tid); \
    RDA(A0N, aA0, aA1, ((CUR) ^ 1) * 32768);                                   \
    lgkm<8>();                                                                 \
    __builtin_amdgcn_s_setprio(1);                                             \
    mmq(acc0, 4, A1C, B0C);                                                    \
    __builtin_amdgcn_s_setprio(0);                                             \
    __builtin_amdgcn_sched_barrier(0);                                         \
    __builtin_amdgcn_s_barrier();                                              \
    /* P4: stage A(t+2) both halves; issue b0(t+1); Q4 = a1 x b1 -> acc1 hi */ \
    if ((t) + 2 < NT) {                                                        \
      stage_half(A, lda, m0, ((t) + 2) * 64, 0, As[CUR], tid);                 \
      stage_half(A, lda, m0, ((t) + 2) * 64, 1, As[CUR], tid);                 \
    }                                                                          \
    RDB(B0N, bA0, bA1, ((CUR) ^ 1) * 16384);                                   \
    __builtin_amdgcn_sched_barrier(0);                                         \
    __builtin_amdgcn_s_setprio(1);                                             \
    mmq(acc1, 4, A1C, B1C);                                                    \
    __builtin_amdgcn_s_setprio(0);                                             \
    __builtin_amdgcn_sched_barrier(0);                                         \
    __builtin_amdgcn_s_barrier();                                              \
  }

__global__ __launch_bounds__(512, 2)
void gemm_mlp(const unsigned short* __restrict__ A, int lda,
              const unsigned short* __restrict__ B0,
              const unsigned short* __restrict__ B1,
              const float* __restrict__ bias0, const float* __restrict__ bias1,
              unsigned short* __restrict__ out, int ldc, int K) {
  __shared__ alignas(16) unsigned short As[2][256 * 64];
  __shared__ alignas(16) unsigned short Bs0[2][128 * 64];
  __shared__ alignas(16) unsigned short Bs1[2][128 * 64];

  const int tid = threadIdx.x;
  const int l = tid & 63, w = tid >> 6;
  const int wr = w >> 2, wc = w & 3;
  const int lr = l & 15, lg = l >> 4;

  int m0, n0;
  xcd_map(128, m0, n0);
  const int NT = K >> 6;  // even (K=2048 -> 32)

  f32x4 acc0[8][2], acc1[8][2];
  const f32x4 z4 = {0.f, 0.f, 0.f, 0.f};
#pragma unroll
  for (int i = 0; i < 8; ++i)
#pragma unroll
    for (int j = 0; j < 2; ++j) { acc0[i][j] = z4; acc1[i][j] = z4; }

  const int s7 = lr & 7;
  const unsigned swz0 = (unsigned)((lg ^ s7) << 4);
  const unsigned swz1 = (unsigned)(((4 | lg) ^ s7) << 4);
  const unsigned rA = (unsigned)((wr * 128 + lr) * 128);
  const unsigned rB = (unsigned)((wc * 32 + lr) * 128);
  const unsigned aA0 = ldsoff(&As[0][0]) + rA + swz0;
  const unsigned aA1 = ldsoff(&As[0][0]) + rA + swz1;
  const unsigned bA0 = ldsoff(&Bs0[0][0]) + rB + swz0;
  const unsigned bA1 = ldsoff(&Bs0[0][0]) + rB + swz1;
  const unsigned cA0 = ldsoff(&Bs1[0][0]) + rB + swz0;
  const unsigned cA1 = ldsoff(&Bs1[0][0]) + rB + swz1;

  bf16x8 a0X[4][2], a1X[4][2], b0X[2][2], b1X[2][2];
  bf16x8 a0Y[4][2], a1Y[4][2], b0Y[2][2], b1Y[2][2];

  stage_half(A, lda, m0, 0, 0, As[0], tid);
  stage_half(A, lda, m0, 0, 1, As[0], tid);
  stage_half(B0, K, n0, 0, 0, Bs0[0], tid);
  stage_half(B1, K, n0, 0, 0, Bs1[0], tid);
  stage_half(B0, K, n0, 64, 0, Bs0[1], tid);
  stage_half(B1, K, n0, 64, 0, Bs1[1], tid);
  stage_half(A, lda, m0, 64, 0, As[1], tid);
  stage_half(A, lda, m0, 64, 1, As[1], tid);
  vmc<8>();
  __builtin_amdgcn_s_barrier();
  RDA(a0X, aA0, aA1, 0);
  RDB(b0X, bA0, bA1, 0);

  for (int t = 0; t < NT; t += 2) {
    MLP_ITER(t, 0, a0X, b0X, b1X, a1X, a0Y, b0Y);
    MLP_ITER(t + 1, 1, a0Y, b0Y, b1Y, a1Y, a0X, b0X);
  }

  // epilogue: out bf16 = (acc0+bias0) * silu(acc1+bias1)
#pragma unroll
  for (int i = 0; i < 8; ++i) {
    int r0 = m0 + wr * 128 + i * 16 + lg * 4;
#pragma unroll
    for (int j = 0; j < 2; ++j) {
      int col = n0 + wc * 32 + j * 16 + lr;
      float bb0 = bias0[col];
      float bb1 = bias1[col];
#pragma unroll
      for (int q = 0; q < 4; ++q) {
        size_t off = (size_t)(r0 + q) * ldc + col;
        float v = acc0[i][j][q] + bb0;
        float gt = acc1[i][j][q] + bb1;
        out[off] = f2bf(v * (gt / (1.f + expf(-gt))));
      }
    }
  }
}

// ---------- flash attention: one q-tile per block, heavy-first, XCD-local ----
// Grid 1024: xcd = g&7, bh = xcd*4 + (slot&3), qb = 31-(slot>>2) so the
// heaviest q-tiles dispatch first (dynamic balancing of the causal triangle).
// 3 blocks/CU (LDS 43008, launch_bounds(256,3)) -> 12 waves/CU to overlap the
// per-iter barrier + softmax dependency chains across blocks. Inner c-loop is
// byte-identical to the verified r3 version; epilogue stages through Ps (wave-
// private) in 2 chunks instead of a dedicated Ob buffer.
__global__ __launch_bounds__(256, 3)
void attn_kernel(const unsigned short* __restrict__ qkv,
                 const unsigned short* __restrict__ vT,
                 unsigned short* __restrict__ ctx) {
  __shared__ unsigned short Ks[64 * 128];
  __shared__ unsigned short Vs[128 * 64];
  __shared__ unsigned short Ps[4][16 * 80];

  const int g = blockIdx.x;
  const int xcd = g & 7, slot = g >> 3;
  const int bh = xcd * 4 + (slot & 3);
  const int qb = 31 - (slot >> 2);
  const int b = bh >> 4, h = bh & 15;
  const int tid = threadIdx.x, l = tid & 63, w = tid >> 6;
  const int lr = l & 15, lg = l >> 4;
  const float slope2 = exp2f(-0.5f * (float)(h + 1)) * 1.44269504f;
  const float SC2 = 0.0078125f * 1.44269504f;

  const int krow = tid >> 4, kcb = tid & 15;
  const int vrow = tid >> 3, vcb = tid & 7;
  const unsigned short* kbase = qkv + (size_t)(b * 2048 + krow) * 6144 + 2048 + h * 128 + kcb * 8;
  const unsigned short* vbase = vT + (size_t)(bh * 128 + vrow) * 2048 + vcb * 8;
  char* kdst = (char*)Ks + krow * 256 + ((kcb ^ (krow & 7)) << 4);
  char* vdst = (char*)Vs + vrow * 128 + ((vcb ^ (vrow & 7)) << 4);

  int4 kr[4], vr[4];
#pragma unroll
  for (int p = 0; p < 4; ++p) {
    kr[p] = *(const int4*)(kbase + (size_t)p * 16 * 6144);
    vr[p] = *(const int4*)(vbase + (size_t)p * 32 * 2048);
  }

  const int q0 = qb * 64;
  bf16x8 aq[4];
  {
    const unsigned short* qp =
        qkv + (size_t)(b * 2048 + q0 + w * 16 + lr) * 6144 + h * 128 + lg * 8;
#pragma unroll
    for (int kk = 0; kk < 4; ++kk) aq[kk] = *(const bf16x8*)(qp + kk * 32);
  }
  const f32x4 z4 = {0.f, 0.f, 0.f, 0.f};
  f32x4 acc[8];
#pragma unroll
  for (int dt = 0; dt < 8; ++dt) acc[dt] = z4;
  float m_r[4] = {-INFINITY, -INFINITY, -INFINITY, -INFINITY};
  float l_r[4] = {0.f, 0.f, 0.f, 0.f};
  const int ibase = q0 + w * 16 + lg * 4;
  const int nc = qb + 1;

  for (int c = 0; c < nc; ++c) {
    const int kv0 = c * 64;
    __syncthreads();
#pragma unroll
    for (int p = 0; p < 4; ++p) {
      *(int4*)(kdst + p * 4096) = kr[p];
      *(int4*)(vdst + p * 4096) = vr[p];
    }
    __syncthreads();
    if (c + 1 < nc) {
      int nxt = (c + 1) * 64;
#pragma unroll
      for (int p = 0; p < 4; ++p) {
        kr[p] = *(const int4*)(kbase + (size_t)nxt * 6144 + (size_t)p * 16 * 6144);
        vr[p] = *(const int4*)(vbase + nxt + (size_t)p * 32 * 2048);
      }
    }

    f32x4 sc[4];
#pragma unroll
    for (int t = 0; t < 4; ++t) sc[t] = z4;
    __builtin_amdgcn_s_setprio(1);
#pragma unroll
    for (int t = 0; t < 4; ++t) {
#pragma unroll
      for (int kk = 0; kk < 4; ++kk) {
        int row = t * 16 + lr;
        int bo = (row * 256 + kk * 64 + lg * 16) ^ ((row & 7) << 4);
        bf16x8 bk = *(const bf16x8*)((const char*)Ks + bo);
        sc[t] = __builtin_amdgcn_mfma_f32_16x16x32_bf16(aq[kk], bk, sc[t], 0, 0, 0);
      }
    }
    __builtin_amdgcn_s_setprio(0);
    float cmax[4] = {-INFINITY, -INFINITY, -INFINITY, -INFINITY};
#pragma unroll
    for (int t = 0; t < 4; ++t)
#pragma unroll
      for (int q = 0; q < 4; ++q) {
        int j = kv0 + t * 16 + lr;
        int i = ibase + q;
        float s = sc[t][q] * SC2 + slope2 * (float)(j - i);
        if (j > i) s = -1e9f;
        sc[t][q] = s;
        cmax[q] = fmaxf(cmax[q], s);
      }
#pragma unroll
    for (int q = 0; q < 4; ++q) {
      float v = cmax[q];
      v = fmaxf(v, __shfl_xor(v, 1));
      v = fmaxf(v, __shfl_xor(v, 2));
      v = fmaxf(v, __shfl_xor(v, 4));
      v = fmaxf(v, __shfl_xor(v, 8));
      cmax[q] = v;
    }
    float alpha[4], rsum[4];
#pragma unroll
    for (int q = 0; q < 4; ++q) {
      float mn = fmaxf(m_r[q], cmax[q]);
      alpha[q] = exp2f(m_r[q] - mn);
      m_r[q] = mn;
      rsum[q] = 0.f;
    }
#pragma unroll
    for (int t = 0; t < 4; ++t)
#pragma unroll
      for (int q = 0; q < 4; ++q) {
        float p = exp2f(sc[t][q] - m_r[q]);
        rsum[q] += p;
        sc[t][q] = p;
      }
#pragma unroll
    for (int q = 0; q < 4; ++q) {
      float v = rsum[q];
      v += __shfl_xor(v, 1);
      v += __shfl_xor(v, 2);
      v += __shfl_xor(v, 4);
      v += __shfl_xor(v, 8);
      l_r[q] = l_r[q] * alpha[q] + v;
    }
#pragma unroll
    for (int dt = 0; dt < 8; ++dt)
#pragma unroll
      for (int q = 0; q < 4; ++q) acc[dt][q] *= alpha[q];
#pragma unroll
    for (int t = 0; t < 4; ++t)
#pragma unroll
      for (int q = 0; q < 4; ++q)
        Ps[w][(lg * 4 + q) * 80 + t * 16 + lr] = f2bf(sc[t][q]);
    __builtin_amdgcn_s_setprio(1);
#pragma unroll
    for (int kc = 0; kc < 2; ++kc) {
      bf16x8 ap = *(const bf16x8*)(&Ps[w][lr * 80 + kc * 32 + lg * 8]);
#pragma unroll
      for (int dt = 0; dt < 8; ++dt) {
        int row = dt * 16 + lr;
        int bo = (row * 128 + kc * 64 + lg * 16) ^ ((row & 7) << 4);
        bf16x8 bv = *(const bf16x8*)((const char*)Vs + bo);
        acc[dt] = __builtin_amdgcn_mfma_f32_16x16x32_bf16(ap, bv, acc[dt], 0, 0, 0);
      }
    }
    __builtin_amdgcn_s_setprio(0);
  }

  // ---- epilogue: per-wave 2-chunk staging through Ps, coalesced 16B stores --
  float inv4[4];
#pragma unroll
  for (int q = 0; q < 4; ++q) inv4[q] = 1.f / l_r[q];
  const int rr = l >> 2, c4 = l & 3;
#pragma unroll
  for (int chv = 0; chv < 2; ++chv) {
#pragma unroll
    for (int q = 0; q < 4; ++q) {
      int rl = lg * 4 + q;
#pragma unroll
      for (int dt = 0; dt < 4; ++dt)
        Ps[w][rl * 80 + dt * 16 + lr] = f2bf(acc[chv * 4 + dt][q] * inv4[q]);
    }
    const unsigned short* srow = &Ps[w][rr * 80 + c4 * 8];
    size_t gb = (size_t)(b * 2048 + q0 + w * 16 + rr) * 2048 + h * 128 + chv * 64 + c4 * 8;
    *(s16x8*)(ctx + gb) = *(const s16x8*)(srow);
    *(s16x8*)(ctx + gb + 32) = *(const s16x8*)(srow + 32);
  }
}

// ---------- launch ----------
extern "C" void kernel_launch(void* const* d_in, const int* in_sizes, int n_in,
                              void* d_out, int out_size, void* d_ws, size_t ws_size,
                              hipStream_t stream) {
  const float* hs   = (const float*)d_in[0];
  const float* ln1g = (const float*)d_in[3];
  const float* ln1b = (const float*)d_in[4];
  const float* wqkv = (const float*)d_in[5];
  const float* bqkv = (const float*)d_in[6];
  const float* wo   = (const float*)d_in[7];
  const float* bo   = (const float*)d_in[8];
  const float* ln2g = (const float*)d_in[9];
  const float* ln2b = (const float*)d_in[10];
  const float* wfc  = (const float*)d_in[11];
  const float* bfc  = (const float*)d_in[12];
  const float* wfc2 = (const float*)d_in[13];
  const float* bfc2 = (const float*)d_in[14];
  const float* wpj  = (const float*)d_in[15];
  const float* bpj  = (const float*)d_in[16];

  char* ws = (char*)d_ws;
  unsigned short* woT   = (unsigned short*)(ws + 0);          //  8 MB
  unsigned short* wfcT  = (unsigned short*)(ws + 8388608);    // 24 MB
  unsigned short* wfc2T = (unsigned short*)(ws + 33554432);   // 24 MB
  unsigned short* hbuf  = (unsigned short*)(ws + 58720256);   // 16 MB
  unsigned short* qkvb  = (unsigned short*)(ws + 75497472);   // 48 MB (later mlp_in)
  unsigned short* wqkvT = (unsigned short*)(ws + 125829120);  // 24 MB (later wpjT)
  unsigned short* vTb   = (unsigned short*)(ws + 150994944);  // 16 MB
  unsigned short* ctxb  = (unsigned short*)(ws + 167772160);  // 16 MB
  unsigned short* wpjT  = wqkvT;
  float* outf = (float*)d_out;

  dim3 blk(256), blk512(512);
  transpose_cast_f32<<<dim3(96, 32), blk, 0, stream>>>(wqkv, wqkvT, 2048, 6144);
  transpose_cast_f32<<<dim3(32, 32), blk, 0, stream>>>(wo, woT, 2048, 2048);
  transpose_cast_f32<<<dim3(96, 32), blk, 0, stream>>>(wfc, wfcT, 2048, 6144);
  transpose_cast_f32<<<dim3(96, 32), blk, 0, stream>>>(wfc2, wfc2T, 2048, 6144);
  ln_kernel<<<dim3(4096), blk, 0, stream>>>(hs, ln1g, ln1b, hbuf);
  // QKV: [4096,2048] x [6144,2048]^T -> [4096,6144] bf16
  gemm256<0><<<dim3(24, 16), blk512, 0, stream>>>(hbuf, 2048, wqkvT, bqkv, nullptr,
                                                  qkvb, 6144, 2048);
  transpose_v<<<dim3(32, 2, 32), blk, 0, stream>>>(qkvb, vTb);
  transpose_cast_f32<<<dim3(32, 96), blk, 0, stream>>>(wpj, wpjT, 6144, 2048);
  // attention (one q-tile per block, heavy-first, XCD-local bh)
  attn_kernel<<<dim3(1024), blk, 0, stream>>>(qkvb, vTb, ctxb);
  // O-proj + residual -> d_out f32
  gemm_n128<1, false><<<dim3(16, 16), blk512, 0, stream>>>(
      ctxb, 2048, woT, nullptr, bo, nullptr, hs, d_out, 2048, 2048);
  ln_kernel<<<dim3(4096), blk, 0, stream>>>(outf, ln2g, ln2b, hbuf);
  // fused MLP gate/up: out = (h2@wfc + bfc) * silu(h2@wfc2 + bfc2)
  gemm_mlp<<<dim3(48, 16), blk512, 0, stream>>>(
      hbuf, 2048, wfcT, wfc2T, bfc, bfc2, qkvb, 6144, 2048);
  // proj + residual -> d_out
  gemm_n128<1, false><<<dim3(16, 16), blk512, 0, stream>>>(
      qkvb, 6144, wpjT, nullptr, bpj, nullptr, outf, d_out, 2048, 6144);
}

// Round 8
// 715.656 us; speedup vs baseline: 1.0111x; 1.0111x over previous
//
#include <hip/hip_runtime.h>
#include <hip/hip_bf16.h>
#include <math.h>

#define DI __device__ __forceinline__

typedef __bf16 bf16x8 __attribute__((ext_vector_type(8)));
typedef float f32x4 __attribute__((ext_vector_type(4)));
typedef short s16x8 __attribute__((ext_vector_type(8)));

// ---------- helpers ----------
DI unsigned short f2bf(float f) {
  unsigned int u = __builtin_bit_cast(unsigned int, f);
  unsigned int r = (u + 0x7fffu + ((u >> 16) & 1u)) >> 16;
  return (unsigned short)r;
}
DI float bf2f(unsigned short h) {
  unsigned int u = ((unsigned int)h) << 16;
  return __builtin_bit_cast(float, u);
}

DI void gload16(const void* g, void* l) {
  __builtin_amdgcn_global_load_lds(
      (const __attribute__((address_space(1))) void*)g,
      (__attribute__((address_space(3))) void*)l, 16, 0, 0);
}

DI unsigned ldsoff(const void* p) {
  return (unsigned)(size_t)(const __attribute__((address_space(3))) void*)p;
}

// asm ds_read_b128 with compile-time offset: compiler cannot sink/elide it.
template <int OFF>
DI bf16x8 ds128(unsigned base) {
  bf16x8 r;
  asm volatile("ds_read_b128 %0, %1 offset:%2" : "=v"(r) : "v"(base), "i"(OFF));
  return r;
}
// counted waits + sched_barrier(0) (MFMA intrinsics can hoist past bare
// inline-asm waitcnt; the sched_barrier pins them below).
template <int N>
DI void lgkm() {
  asm volatile("s_waitcnt lgkmcnt(%0)" ::"i"(N));
  __builtin_amdgcn_sched_barrier(0);
}
template <int N>
DI void vmc() {
  asm volatile("s_waitcnt vmcnt(%0)" ::"i"(N));
  __builtin_amdgcn_sched_barrier(0);
}

// 2-D XCD rasterization for GEMMs.
DI void xcd_map(int BN, int& m0, int& n0) {
  const int nx = gridDim.x;
  int orig = blockIdx.y * nx + blockIdx.x;
  int xcd = orig & 7, k = orig >> 3;
  int xm = xcd >> 2, xn = xcd & 3;
  int nband = nx >> 2;
  m0 = (xm * 8 + (k & 7)) * 256;
  n0 = (xn * nband + (k >> 3)) * BN;
}

// ---------- transpose + fp32->bf16 cast ----------
__global__ __launch_bounds__(256)
void transpose_cast_f32(const float* __restrict__ in, unsigned short* __restrict__ out,
                        int R, int C) {
  __shared__ unsigned int t[64 * 65];
  const int r0 = blockIdx.y * 64, c0 = blockIdx.x * 64;
  const int tid = threadIdx.x;
#pragma unroll
  for (int p = 0; p < 4; ++p) {
    int e = p * 1024 + tid * 4;
    int r = e >> 6, c = e & 63;
    float4 v = *(const float4*)(in + (size_t)(r0 + r) * C + c0 + c);
    t[r * 65 + c + 0] = f2bf(v.x);
    t[r * 65 + c + 1] = f2bf(v.y);
    t[r * 65 + c + 2] = f2bf(v.z);
    t[r * 65 + c + 3] = f2bf(v.w);
  }
  __syncthreads();
  const int oc = tid >> 2, ch = tid & 3;
  alignas(16) unsigned short vals[16];
#pragma unroll
  for (int j = 0; j < 16; ++j) vals[j] = (unsigned short)t[(ch * 16 + j) * 65 + oc];
  size_t ob = (size_t)(c0 + oc) * R + r0 + ch * 16;
  *(s16x8*)(out + ob) = *(const s16x8*)(vals);
  *(s16x8*)(out + ob + 8) = *(const s16x8*)(vals + 8);
}

// ---------- V transpose ----------
__global__ __launch_bounds__(256)
void transpose_v(const unsigned short* __restrict__ qkv, unsigned short* __restrict__ vT) {
  __shared__ unsigned int t[64 * 65];
  const int s0 = blockIdx.x * 64, d0 = blockIdx.y * 64, bh = blockIdx.z;
  const int b = bh >> 4, h = bh & 15;
  const int tid = threadIdx.x;
#pragma unroll
  for (int p = 0; p < 2; ++p) {
    int id = p * 256 + tid;
    int r = id >> 3, c = (id & 7) * 8;
    s16x8 v = *(const s16x8*)(qkv + (size_t)(b * 2048 + s0 + r) * 6144 + 4096 + h * 128 + d0 + c);
#pragma unroll
    for (int j = 0; j < 8; ++j) t[r * 65 + c + j] = (unsigned short)((const unsigned short*)&v)[j];
  }
  __syncthreads();
  const int oc = tid >> 2, ch = tid & 3;
  alignas(16) unsigned short vals[16];
#pragma unroll
  for (int j = 0; j < 16; ++j) vals[j] = (unsigned short)t[(ch * 16 + j) * 65 + oc];
  size_t ob = (size_t)(bh * 128 + d0 + oc) * 2048 + s0 + ch * 16;
  *(s16x8*)(vT + ob) = *(const s16x8*)(vals);
  *(s16x8*)(vT + ob + 8) = *(const s16x8*)(vals + 8);
}

// ---------- LayerNorm fp32 -> bf16, row = 2048 ----------
__global__ __launch_bounds__(256)
void ln_kernel(const float* __restrict__ x, const float* __restrict__ g,
               const float* __restrict__ bi, unsigned short* __restrict__ y) {
  __shared__ float red[8];
  const int row = blockIdx.x, tid = threadIdx.x;
  const float* xp = x + (size_t)row * 2048 + tid * 8;
  float4 v0 = *(const float4*)xp;
  float4 v1 = *(const float4*)(xp + 4);
  float v[8] = {v0.x, v0.y, v0.z, v0.w, v1.x, v1.y, v1.z, v1.w};
  float s = 0.f;
#pragma unroll
  for (int j = 0; j < 8; ++j) s += v[j];
#pragma unroll
  for (int d = 1; d < 64; d <<= 1) s += __shfl_xor(s, d);
  if ((tid & 63) == 0) red[tid >> 6] = s;
  __syncthreads();
  float mean = (red[0] + red[1] + red[2] + red[3]) * (1.f / 2048.f);
  float dd[8], sq = 0.f;
#pragma unroll
  for (int j = 0; j < 8; ++j) { dd[j] = v[j] - mean; sq += dd[j] * dd[j]; }
#pragma unroll
  for (int d = 1; d < 64; d <<= 1) sq += __shfl_xor(sq, d);
  if ((tid & 63) == 0) red[4 + (tid >> 6)] = sq;
  __syncthreads();
  float var = (red[4] + red[5] + red[6] + red[7]) * (1.f / 2048.f);
  float rs = rsqrtf(var + 1e-5f);
  float4 g0 = *(const float4*)(g + tid * 8), g1 = *(const float4*)(g + tid * 8 + 4);
  float4 b0 = *(const float4*)(bi + tid * 8), b1 = *(const float4*)(bi + tid * 8 + 4);
  float gg[8] = {g0.x, g0.y, g0.z, g0.w, g1.x, g1.y, g1.z, g1.w};
  float bb[8] = {b0.x, b0.y, b0.z, b0.w, b1.x, b1.y, b1.z, b1.w};
  alignas(16) unsigned short o[8];
#pragma unroll
  for (int j = 0; j < 8; ++j) o[j] = f2bf(dd[j] * rs * gg[j] + bb[j]);
  *(s16x8*)(y + (size_t)row * 2048 + tid * 8) = *(const s16x8*)o;
}

// ---------- shared GEMM staging ----------
DI void stage_half(const unsigned short* __restrict__ G, int ld, int rbase, int kt,
                   int h, unsigned short* dst, int tid) {
#pragma unroll
  for (int i = 0; i < 2; ++i) {
    int id = i * 512 + tid;
    int rl = id >> 3, sl = id & 7;
    int ss = sl ^ (rl & 7);
    gload16(G + (size_t)(rbase + h * 128 + rl) * ld + kt + ss * 8,
            (char*)dst + h * 16384 + id * 16);
  }
}

#define RDA(dst, B0_, B1_, OFS)                                        \
  dst[0][0] = ds128<(OFS) + 0>(B0_);    dst[0][1] = ds128<(OFS) + 0>(B1_);    \
  dst[1][0] = ds128<(OFS) + 2048>(B0_); dst[1][1] = ds128<(OFS) + 2048>(B1_); \
  dst[2][0] = ds128<(OFS) + 4096>(B0_); dst[2][1] = ds128<(OFS) + 4096>(B1_); \
  dst[3][0] = ds128<(OFS) + 6144>(B0_); dst[3][1] = ds128<(OFS) + 6144>(B1_);

#define RDB(dst, B0_, B1_, OFS)                                        \
  dst[0][0] = ds128<(OFS) + 0>(B0_);    dst[0][1] = ds128<(OFS) + 0>(B1_);    \
  dst[1][0] = ds128<(OFS) + 2048>(B0_); dst[1][1] = ds128<(OFS) + 2048>(B1_);

// ---------- 256x256 GEMM (QKV): counted-asm pipelined, 4 clusters/K-tile ----
// (r4-verified: b23 drains under Q1, a1 under Q2; vmcnt(6) ledger.)
// MODE 0: out bf16 = acc + bias ; MODE 1: out f32 = acc + bias + res
template <int MODE>
__global__ __launch_bounds__(512, 2)
void gemm256(const unsigned short* __restrict__ A, int lda,
             const unsigned short* __restrict__ B,
             const float* __restrict__ bias,
             const void* __restrict__ resg,
             void* __restrict__ out, int ldc, int K) {
  __shared__ alignas(16) unsigned short As[2][256 * 64];
  __shared__ alignas(16) unsigned short Bs[2][256 * 64];

  const int tid = threadIdx.x;
  const int l = tid & 63, w = tid >> 6;
  const int wr = w >> 2, wc = w & 3;
  const int lr = l & 15, lg = l >> 4;

  int m0, n0;
  xcd_map(256, m0, n0);

  const int NT = K >> 6;

  f32x4 acc[8][4];
  const f32x4 z4 = {0.f, 0.f, 0.f, 0.f};
#pragma unroll
  for (int i = 0; i < 8; ++i)
#pragma unroll
    for (int j = 0; j < 4; ++j) acc[i][j] = z4;

  const int s7 = lr & 7;
  const unsigned swz0 = (unsigned)((lg ^ s7) << 4);
  const unsigned swz1 = (unsigned)(((4 | lg) ^ s7) << 4);
  const unsigned rA = (unsigned)((wr * 128 + lr) * 128);
  const unsigned rB = (unsigned)((wc * 64 + lr) * 128);
  const unsigned aA0 = ldsoff(&As[0][0]) + rA + swz0;
  const unsigned aA1 = ldsoff(&As[0][0]) + rA + swz1;
  const unsigned bA0 = ldsoff(&Bs[0][0]) + rB + swz0;
  const unsigned bA1 = ldsoff(&Bs[0][0]) + rB + swz1;

  stage_half(A, lda, m0, 0, 0, As[0], tid);
  stage_half(A, lda, m0, 0, 1, As[0], tid);
  stage_half(B, K, n0, 0, 0, Bs[0], tid);
  stage_half(B, K, n0, 0, 1, Bs[0], tid);
  if (NT > 1) {
    stage_half(B, K, n0, 64, 0, Bs[1], tid);
    stage_half(B, K, n0, 64, 1, Bs[1], tid);
    stage_half(A, lda, m0, 64, 0, As[1], tid);
    asm volatile("s_waitcnt vmcnt(6)" ::: "memory");
  } else {
    asm volatile("s_waitcnt vmcnt(0)" ::: "memory");
  }
  __builtin_amdgcn_s_barrier();

  for (int t = 0; t < NT; ++t) {
    const unsigned co = (unsigned)((t & 1) * 32768);
    const unsigned a0b = aA0 + co, a1b = aA1 + co;
    const unsigned b0b = bA0 + co, b1b = bA1 + co;
    bf16x8 a0[4][2], a1[4][2], bfr[4][2];

    // ---- c1: issue a0(8)+b01(4); stage Ah1(t+1); issue b23(4); lgkm<4>;
    //      Q1 = a0 x b01 (b23 drains underneath) ----
#pragma unroll
    for (int i = 0; i < 4; ++i) {
      a0[i][0] = ds128<0>(a0b + i * 2048);
      a0[i][1] = ds128<0>(a1b + i * 2048);
    }
#pragma unroll
    for (int j = 0; j < 2; ++j) {
      bfr[j][0] = ds128<0>(b0b + j * 2048);
      bfr[j][1] = ds128<0>(b1b + j * 2048);
    }
    if (t + 1 < NT) stage_half(A, lda, m0, (t + 1) * 64, 1, As[(t & 1) ^ 1], tid);
#pragma unroll
    for (int j = 2; j < 4; ++j) {
      bfr[j][0] = ds128<0>(b0b + j * 2048);
      bfr[j][1] = ds128<0>(b1b + j * 2048);
    }
    lgkm<4>();
    __builtin_amdgcn_s_setprio(1);
#pragma unroll
    for (int i = 0; i < 4; ++i)
#pragma unroll
      for (int j = 0; j < 2; ++j)
#pragma unroll
        for (int kk = 0; kk < 2; ++kk)
          acc[i][j] = __builtin_amdgcn_mfma_f32_16x16x32_bf16(a0[i][kk], bfr[j][kk], acc[i][j], 0, 0, 0);
    __builtin_amdgcn_s_setprio(0);
    __builtin_amdgcn_s_barrier();

    // ---- c2: issue a1(8); lgkm<8> (drains b23); Q2 = a0 x b23 ----
#pragma unroll
    for (int i = 0; i < 4; ++i) {
      a1[i][0] = ds128<8192>(a0b + i * 2048);
      a1[i][1] = ds128<8192>(a1b + i * 2048);
    }
    lgkm<8>();
    __builtin_amdgcn_s_setprio(1);
#pragma unroll
    for (int i = 0; i < 4; ++i)
#pragma unroll
      for (int j = 2; j < 4; ++j)
#pragma unroll
        for (int kk = 0; kk < 2; ++kk)
          acc[i][j] = __builtin_amdgcn_mfma_f32_16x16x32_bf16(a0[i][kk], bfr[j][kk], acc[i][j], 0, 0, 0);
    __builtin_amdgcn_s_setprio(0);
    __builtin_amdgcn_s_barrier();

    // ---- c3: stage Bh0(t+2); lgkm<0> (drains a1); Q3 = a1 x b01 ----
    if (t + 2 < NT) stage_half(B, K, n0, (t + 2) * 64, 0, Bs[t & 1], tid);
    lgkm<0>();
    __builtin_amdgcn_s_setprio(1);
#pragma unroll
    for (int i = 0; i < 4; ++i)
#pragma unroll
      for (int j = 0; j < 2; ++j)
#pragma unroll
        for (int kk = 0; kk < 2; ++kk)
          acc[i + 4][j] = __builtin_amdgcn_mfma_f32_16x16x32_bf16(a1[i][kk], bfr[j][kk], acc[i + 4][j], 0, 0, 0);
    __builtin_amdgcn_s_setprio(0);
    __builtin_amdgcn_s_barrier();

    // ---- c4: stage Bh1(t+2)+Ah0(t+2); Q4 = a1 x b23; vmc ----
    if (t + 2 < NT) {
      stage_half(B, K, n0, (t + 2) * 64, 1, Bs[t & 1], tid);
      stage_half(A, lda, m0, (t + 2) * 64, 0, As[t & 1], tid);
    }
    __builtin_amdgcn_s_setprio(1);
#pragma unroll
    for (int i = 0; i < 4; ++i)
#pragma unroll
      for (int j = 2; j < 4; ++j)
#pragma unroll
        for (int kk = 0; kk < 2; ++kk)
          acc[i + 4][j] = __builtin_amdgcn_mfma_f32_16x16x32_bf16(a1[i][kk], bfr[j][kk], acc[i + 4][j], 0, 0, 0);
    __builtin_amdgcn_s_setprio(0);
    if (t + 2 < NT) { vmc<6>(); } else { vmc<0>(); }
    __builtin_amdgcn_s_barrier();
  }

#pragma unroll
  for (int i = 0; i < 8; ++i) {
    int r0 = m0 + wr * 128 + i * 16 + lg * 4;
#pragma unroll
    for (int j = 0; j < 4; ++j) {
      int col = n0 + wc * 64 + j * 16 + lr;
      float bb = bias[col];
#pragma unroll
      for (int q = 0; q < 4; ++q) {
        size_t off = (size_t)(r0 + q) * ldc + col;
        float v = acc[i][j][q] + bb;
        if (MODE == 0) {
          ((unsigned short*)out)[off] = f2bf(v);
        } else {
          ((float*)out)[off] = v + ((const float*)resg)[off];
        }
      }
    }
  }
}

// ---------- 256x128 GEMM single-B (O-proj / proj): counted-asm 2-cluster ----
template <int MODE, bool DUAL>
__global__ __launch_bounds__(512, 2)
void gemm_n128(const unsigned short* __restrict__ A, int lda,
               const unsigned short* __restrict__ B0,
               const unsigned short* __restrict__ B1,
               const float* __restrict__ bias0, const float* __restrict__ bias1,
               const void* __restrict__ resg,
               void* __restrict__ out, int ldc, int K) {
  __shared__ alignas(16) unsigned short As[2][256 * 64];
  __shared__ alignas(16) unsigned short Bs0[2][128 * 64];

  const int tid = threadIdx.x;
  const int l = tid & 63, w = tid >> 6;
  const int wr = w >> 2, wc = w & 3;
  const int lr = l & 15, lg = l >> 4;

  int m0, n0;
  xcd_map(128, m0, n0);

  const int NT = K >> 6;

  f32x4 acc0[8][2];
  const f32x4 z4 = {0.f, 0.f, 0.f, 0.f};
#pragma unroll
  for (int i = 0; i < 8; ++i)
#pragma unroll
    for (int j = 0; j < 2; ++j) acc0[i][j] = z4;

  const int s7 = lr & 7;
  const unsigned swz0 = (unsigned)((lg ^ s7) << 4);
  const unsigned swz1 = (unsigned)(((4 | lg) ^ s7) << 4);
  const unsigned rA = (unsigned)((wr * 128 + lr) * 128);
  const unsigned rB = (unsigned)((wc * 32 + lr) * 128);
  const unsigned aA0 = ldsoff(&As[0][0]) + rA + swz0;
  const unsigned aA1 = ldsoff(&As[0][0]) + rA + swz1;
  const unsigned bA0 = ldsoff(&Bs0[0][0]) + rB + swz0;
  const unsigned bA1 = ldsoff(&Bs0[0][0]) + rB + swz1;

  // prologue
  stage_half(A, lda, m0, 0, 0, As[0], tid);
  stage_half(A, lda, m0, 0, 1, As[0], tid);
  stage_half(B0, K, n0, 0, 0, Bs0[0], tid);
  if (NT > 1) {
    stage_half(B0, K, n0, 64, 0, Bs0[1], tid);
    stage_half(A, lda, m0, 64, 0, As[1], tid);
    asm volatile("s_waitcnt vmcnt(4)" ::: "memory");
  } else {
    asm volatile("s_waitcnt vmcnt(0)" ::: "memory");
  }
  __builtin_amdgcn_s_barrier();

  for (int t = 0; t < NT; ++t) {
    const int cur = t & 1;
    const unsigned ca = aA0 + (unsigned)(cur * 32768);
    const unsigned ca1 = aA1 + (unsigned)(cur * 32768);
    const unsigned cb = bA0 + (unsigned)(cur * 16384);
    const unsigned cb1 = bA1 + (unsigned)(cur * 16384);
    bf16x8 a0[4][2], a1[4][2], b0f[2][2];

    // ---- c1: issue a0(8)+b0(4); stage Ah1(t+1); issue a1(8); lgkm<8>;
    //      Q1 = a0 x b0 (a1 drains underneath) ----
#pragma unroll
    for (int i = 0; i < 4; ++i) {
      a0[i][0] = ds128<0>(ca + i * 2048);
      a0[i][1] = ds128<0>(ca1 + i * 2048);
    }
#pragma unroll
    for (int j = 0; j < 2; ++j) {
      b0f[j][0] = ds128<0>(cb + j * 2048);
      b0f[j][1] = ds128<0>(cb1 + j * 2048);
    }
    if (t + 1 < NT) stage_half(A, lda, m0, (t + 1) * 64, 1, As[cur ^ 1], tid);
#pragma unroll
    for (int i = 0; i < 4; ++i) {
      a1[i][0] = ds128<8192>(ca + i * 2048);
      a1[i][1] = ds128<8192>(ca1 + i * 2048);
    }
    lgkm<8>();
    __builtin_amdgcn_s_setprio(1);
#pragma unroll
    for (int i = 0; i < 4; ++i)
#pragma unroll
      for (int j = 0; j < 2; ++j)
#pragma unroll
        for (int kk = 0; kk < 2; ++kk)
          acc0[i][j] = __builtin_amdgcn_mfma_f32_16x16x32_bf16(a0[i][kk], b0f[j][kk], acc0[i][j], 0, 0, 0);
    __builtin_amdgcn_s_setprio(0);
    __builtin_amdgcn_s_barrier();

    // ---- c2: stage B0(t+2); lgkm<0> (drain a1); stage Ah0(t+2); Q2 ----
    if (t + 2 < NT) stage_half(B0, K, n0, (t + 2) * 64, 0, Bs0[cur], tid);
    lgkm<0>();
    if (t + 2 < NT) stage_half(A, lda, m0, (t + 2) * 64, 0, As[cur], tid);
    __builtin_amdgcn_s_setprio(1);
#pragma unroll
    for (int i = 0; i < 4; ++i)
#pragma unroll
      for (int j = 0; j < 2; ++j)
#pragma unroll
        for (int kk = 0; kk < 2; ++kk)
          acc0[i + 4][j] = __builtin_amdgcn_mfma_f32_16x16x32_bf16(a1[i][kk], b0f[j][kk], acc0[i + 4][j], 0, 0, 0);
    __builtin_amdgcn_s_setprio(0);
    if (t + 2 < NT) { vmc<4>(); } else { vmc<0>(); }
    __builtin_amdgcn_s_barrier();
  }

  // epilogue
#pragma unroll
  for (int i = 0; i < 8; ++i) {
    int r0 = m0 + wr * 128 + i * 16 + lg * 4;
#pragma unroll
    for (int j = 0; j < 2; ++j) {
      int col = n0 + wc * 32 + j * 16 + lr;
      float bb0 = bias0[col];
#pragma unroll
      for (int q = 0; q < 4; ++q) {
        size_t off = (size_t)(r0 + q) * ldc + col;
        float v = acc0[i][j][q] + bb0;
        ((float*)out)[off] = v + ((const float*)resg)[off];
      }
    }
  }
}

// ---------- MLP dual GEMM: 256x128, counted-wait asm-pipelined 4-phase ------
// (r2/r4-verified schedule)
DI void mmq(f32x4 (&acc)[8][2], int io, const bf16x8 (&af)[4][2], const bf16x8 (&bf)[2][2]) {
#pragma unroll
  for (int kk = 0; kk < 2; ++kk)
#pragma unroll
    for (int i = 0; i < 4; ++i)
#pragma unroll
      for (int j = 0; j < 2; ++j)
        acc[io + i][j] = __builtin_amdgcn_mfma_f32_16x16x32_bf16(af[i][kk], bf[j][kk], acc[io + i][j], 0, 0, 0);
}

#define MLP_ITER(t, CUR, A0C, B0C, B1C, A1C, A0N, B0N)                         \
  {                                                                            \
    /* P1: issue b1(t); wait a0(t),b0(t); Q1 = a0 x b0 -> acc0 lo */           \
    RDB(B1C, cA0, cA1, (CUR) * 16384);                                         \
    lgkm<4>();                                                                 \
    __builtin_amdgcn_s_setprio(1);                                             \
    mmq(acc0, 0, A0C, B0C);                                                    \
    __builtin_amdgcn_s_setprio(0);                                             \
    __builtin_amdgcn_sched_barrier(0);                                         \
    __builtin_amdgcn_s_barrier();                                              \
    /* P2: stage B0(t+2); issue a1(t); wait b1(t); Q2 = a0 x b1 -> acc1 lo */  \
    if ((t) + 2 < NT) stage_half(B0, K, n0, ((t) + 2) * 64, 0, Bs0[CUR], tid); \
    RDA(A1C, aA0, aA1, (CUR) * 32768 + 8192);                                  \
    lgkm<8>();                                                                 \
    __builtin_amdgcn_s_setprio(1);                                             \
    mmq(acc1, 0, A0C, B1C);                                                    \
    __builtin_amdgcn_s_setprio(0);                                             \
    if ((t) + 2 < NT) { vmc<2>(); } else { vmc<0>(); }                         \
    __builtin_amdgcn_s_barrier();                                              \
    /* P3: stage B1(t+2); issue a0(t+1); wait a1(t); Q3 = a1 x b0 -> acc0 hi */\
    if ((t) + 2 < NT) stage_half(B1, K, n0, ((t) + 2) * 64, 0, Bs1[CUR], tid); \
    RDA(A0N, aA0, aA1, ((CUR) ^ 1) * 32768);                                   \
    lgkm<8>();                                                                 \
    __builtin_amdgcn_s_setprio(1);                                             \
    mmq(acc0, 4, A1C, B0C);                                                    \
    __builtin_amdgcn_s_setprio(0);                                             \
    __builtin_amdgcn_sched_barrier(0);                                         \
    __builtin_amdgcn_s_barrier();                                              \
    /* P4: stage A(t+2) both halves; issue b0(t+1); Q4 = a1 x b1 -> acc1 hi */ \
    if ((t) + 2 < NT) {                                                        \
      stage_half(A, lda, m0, ((t) + 2) * 64, 0, As[CUR], tid);                 \
      stage_half(A, lda, m0, ((t) + 2) * 64, 1, As[CUR], tid);                 \
    }                                                                          \
    RDB(B0N, bA0, bA1, ((CUR) ^ 1) * 16384);                                   \
    __builtin_amdgcn_sched_barrier(0);                                         \
    __builtin_amdgcn_s_setprio(1);                                             \
    mmq(acc1, 4, A1C, B1C);                                                    \
    __builtin_amdgcn_s_setprio(0);                                             \
    __builtin_amdgcn_sched_barrier(0);                                         \
    __builtin_amdgcn_s_barrier();                                              \
  }

__global__ __launch_bounds__(512, 2)
void gemm_mlp(const unsigned short* __restrict__ A, int lda,
              const unsigned short* __restrict__ B0,
              const unsigned short* __restrict__ B1,
              const float* __restrict__ bias0, const float* __restrict__ bias1,
              unsigned short* __restrict__ out, int ldc, int K) {
  __shared__ alignas(16) unsigned short As[2][256 * 64];
  __shared__ alignas(16) unsigned short Bs0[2][128 * 64];
  __shared__ alignas(16) unsigned short Bs1[2][128 * 64];

  const int tid = threadIdx.x;
  const int l = tid & 63, w = tid >> 6;
  const int wr = w >> 2, wc = w & 3;
  const int lr = l & 15, lg = l >> 4;

  int m0, n0;
  xcd_map(128, m0, n0);
  const int NT = K >> 6;  // even (K=2048 -> 32)

  f32x4 acc0[8][2], acc1[8][2];
  const f32x4 z4 = {0.f, 0.f, 0.f, 0.f};
#pragma unroll
  for (int i = 0; i < 8; ++i)
#pragma unroll
    for (int j = 0; j < 2; ++j) { acc0[i][j] = z4; acc1[i][j] = z4; }

  const int s7 = lr & 7;
  const unsigned swz0 = (unsigned)((lg ^ s7) << 4);
  const unsigned swz1 = (unsigned)(((4 | lg) ^ s7) << 4);
  const unsigned rA = (unsigned)((wr * 128 + lr) * 128);
  const unsigned rB = (unsigned)((wc * 32 + lr) * 128);
  const unsigned aA0 = ldsoff(&As[0][0]) + rA + swz0;
  const unsigned aA1 = ldsoff(&As[0][0]) + rA + swz1;
  const unsigned bA0 = ldsoff(&Bs0[0][0]) + rB + swz0;
  const unsigned bA1 = ldsoff(&Bs0[0][0]) + rB + swz1;
  const unsigned cA0 = ldsoff(&Bs1[0][0]) + rB + swz0;
  const unsigned cA1 = ldsoff(&Bs1[0][0]) + rB + swz1;

  bf16x8 a0X[4][2], a1X[4][2], b0X[2][2], b1X[2][2];
  bf16x8 a0Y[4][2], a1Y[4][2], b0Y[2][2], b1Y[2][2];

  stage_half(A, lda, m0, 0, 0, As[0], tid);
  stage_half(A, lda, m0, 0, 1, As[0], tid);
  stage_half(B0, K, n0, 0, 0, Bs0[0], tid);
  stage_half(B1, K, n0, 0, 0, Bs1[0], tid);
  stage_half(B0, K, n0, 64, 0, Bs0[1], tid);
  stage_half(B1, K, n0, 64, 0, Bs1[1], tid);
  stage_half(A, lda, m0, 64, 0, As[1], tid);
  stage_half(A, lda, m0, 64, 1, As[1], tid);
  vmc<8>();
  __builtin_amdgcn_s_barrier();
  RDA(a0X, aA0, aA1, 0);
  RDB(b0X, bA0, bA1, 0);

  for (int t = 0; t < NT; t += 2) {
    MLP_ITER(t, 0, a0X, b0X, b1X, a1X, a0Y, b0Y);
    MLP_ITER(t + 1, 1, a0Y, b0Y, b1Y, a1Y, a0X, b0X);
  }

  // epilogue: out bf16 = (acc0+bias0) * silu(acc1+bias1)
#pragma unroll
  for (int i = 0; i < 8; ++i) {
    int r0 = m0 + wr * 128 + i * 16 + lg * 4;
#pragma unroll
    for (int j = 0; j < 2; ++j) {
      int col = n0 + wc * 32 + j * 16 + lr;
      float bb0 = bias0[col];
      float bb1 = bias1[col];
#pragma unroll
      for (int q = 0; q < 4; ++q) {
        size_t off = (size_t)(r0 + q) * ldc + col;
        float v = acc0[i][j][q] + bb0;
        float gt = acc1[i][j][q] + bb1;
        out[off] = f2bf(v * (gt / (1.f + expf(-gt))));
      }
    }
  }
}

// ---------- flash attention: paired q-tiles + K/V LDS double-buffer --------
// Grid 512, XCD-local bh (r3-verified mapping). r7's one-q-tile-per-block
// split REGRESSED +33us (doubled per-block overhead, worse balance); the
// paired (pid, 31-pid) decomposition gives every block exactly 33 c-iters.
// New here: K/V double-buffered in LDS -> ONE barrier per c-iter (was 2),
// and the 8 ds_writes overlap softmax/PV instead of sitting between two
// barriers at the head. Buffer parity cur = gi&1 runs continuously across
// the two q-tiles (gi = global iter 0..32). WAR safety: write to buf[cur^1]
// at iter gi vs reads of that buffer at iter gi-1 are separated by gi-1's
// end-of-iter barrier; reads of buf[cur] at gi see gi-1's (pre-barrier)
// write. Epilogue stages through wave-private Ps in 2 chunks (no Ob buffer);
// LDS = 32K(Ks)+32K(Vs)+10K(Ps) = 74KB -> 2 blocks/CU (unchanged).
__global__ __launch_bounds__(256, 2)
void attn_kernel(const unsigned short* __restrict__ qkv,
                 const unsigned short* __restrict__ vT,
                 unsigned short* __restrict__ ctx) {
  __shared__ unsigned short Ks[2][64 * 128];
  __shared__ unsigned short Vs[2][128 * 64];
  __shared__ unsigned short Ps[4][16 * 80];

  const int g = blockIdx.x;
  const int xcd = g & 7, slot = g >> 3;
  const int bh = xcd * 4 + (slot & 3);
  const int pid = slot >> 2;
  const int b = bh >> 4, h = bh & 15;
  const int tid = threadIdx.x, l = tid & 63, w = tid >> 6;
  const int lr = l & 15, lg = l >> 4;
  const float slope2 = exp2f(-0.5f * (float)(h + 1)) * 1.44269504f;
  const float SC2 = 0.0078125f * 1.44269504f;

  const int krow = tid >> 4, kcb = tid & 15;
  const int vrow = tid >> 3, vcb = tid & 7;
  const unsigned short* kbase = qkv + (size_t)(b * 2048 + krow) * 6144 + 2048 + h * 128 + kcb * 8;
  const unsigned short* vbase = vT + (size_t)(bh * 128 + vrow) * 2048 + vcb * 8;
  const int koff = krow * 256 + ((kcb ^ (krow & 7)) << 4);
  const int voff = vrow * 128 + ((vcb ^ (vrow & 7)) << 4);

  const int nc0 = pid + 1;  // tq0 iters; total iters nc0 + (32-pid) = 33

  int4 kr[4], vr[4];
  // tile gi=0 (kv 0): load -> regs -> buf0
#pragma unroll
  for (int p = 0; p < 4; ++p) {
    kr[p] = *(const int4*)(kbase + (size_t)p * 16 * 6144);
    vr[p] = *(const int4*)(vbase + (size_t)p * 32 * 2048);
  }
#pragma unroll
  for (int p = 0; p < 4; ++p) {
    *(int4*)((char*)Ks[0] + koff + p * 4096) = kr[p];
    *(int4*)((char*)Vs[0] + voff + p * 4096) = vr[p];
  }
  // prefetch tile gi=1 into regs (kv 1 if tq0 has it, else tq1's kv 0)
  {
    int nk = ((1 < nc0) ? 1 : 0) * 64;
#pragma unroll
    for (int p = 0; p < 4; ++p) {
      kr[p] = *(const int4*)(kbase + (size_t)nk * 6144 + (size_t)p * 16 * 6144);
      vr[p] = *(const int4*)(vbase + nk + (size_t)p * 32 * 2048);
    }
  }
  __syncthreads();

  for (int tq = 0; tq < 2; ++tq) {
    const int qb = tq ? (31 - pid) : pid;
    const int q0 = qb * 64;
    const int nc = qb + 1;
    const int gb0 = tq ? nc0 : 0;
    bf16x8 aq[4];
    {
      const unsigned short* qp =
          qkv + (size_t)(b * 2048 + q0 + w * 16 + lr) * 6144 + h * 128 + lg * 8;
#pragma unroll
      for (int kk = 0; kk < 4; ++kk) aq[kk] = *(const bf16x8*)(qp + kk * 32);
    }
    const f32x4 z4 = {0.f, 0.f, 0.f, 0.f};
    f32x4 acc[8];
#pragma unroll
    for (int dt = 0; dt < 8; ++dt) acc[dt] = z4;
    float m_r[4] = {-INFINITY, -INFINITY, -INFINITY, -INFINITY};
    float l_r[4] = {0.f, 0.f, 0.f, 0.f};
    const int ibase = q0 + w * 16 + lg * 4;

    for (int c = 0; c < nc; ++c) {
      const int gi = gb0 + c;
      const int cur = gi & 1;
      const char* Kc = (const char*)Ks[cur];
      const char* Vc = (const char*)Vs[cur];
      const int kv0 = c * 64;

      f32x4 sc[4];
#pragma unroll
      for (int t = 0; t < 4; ++t) sc[t] = z4;
      __builtin_amdgcn_s_setprio(1);
#pragma unroll
      for (int t = 0; t < 4; ++t) {
#pragma unroll
        for (int kk = 0; kk < 4; ++kk) {
          int row = t * 16 + lr;
          int bo = (row * 256 + kk * 64 + lg * 16) ^ ((row & 7) << 4);
          bf16x8 bk = *(const bf16x8*)(Kc + bo);
          sc[t] = __builtin_amdgcn_mfma_f32_16x16x32_bf16(aq[kk], bk, sc[t], 0, 0, 0);
        }
      }
      __builtin_amdgcn_s_setprio(0);

      // write tile gi+1 into the other buffer (overlaps softmax/PV below)
      if (gi + 1 < 33) {
        char* kd = (char*)Ks[cur ^ 1] + koff;
        char* vd = (char*)Vs[cur ^ 1] + voff;
#pragma unroll
        for (int p = 0; p < 4; ++p) {
          *(int4*)(kd + p * 4096) = kr[p];
          *(int4*)(vd + p * 4096) = vr[p];
        }
      }
      // prefetch tile gi+2 into regs
      if (gi + 2 < 33) {
        int i2 = gi + 2;
        int nk = ((i2 < nc0) ? i2 : i2 - nc0) * 64;
#pragma unroll
        for (int p = 0; p < 4; ++p) {
          kr[p] = *(const int4*)(kbase + (size_t)nk * 6144 + (size_t)p * 16 * 6144);
          vr[p] = *(const int4*)(vbase + nk + (size_t)p * 32 * 2048);
        }
      }

      float cmax[4] = {-INFINITY, -INFINITY, -INFINITY, -INFINITY};
#pragma unroll
      for (int t = 0; t < 4; ++t)
#pragma unroll
        for (int q = 0; q < 4; ++q) {
          int j = kv0 + t * 16 + lr;
          int i = ibase + q;
          float s = sc[t][q] * SC2 + slope2 * (float)(j - i);
          if (j > i) s = -1e9f;
          sc[t][q] = s;
          cmax[q] = fmaxf(cmax[q], s);
        }
#pragma unroll
      for (int q = 0; q < 4; ++q) {
        float v = cmax[q];
        v = fmaxf(v, __shfl_xor(v, 1));
        v = fmaxf(v, __shfl_xor(v, 2));
        v = fmaxf(v, __shfl_xor(v, 4));
        v = fmaxf(v, __shfl_xor(v, 8));
        cmax[q] = v;
      }
      float alpha[4], rsum[4];
#pragma unroll
      for (int q = 0; q < 4; ++q) {
        float mn = fmaxf(m_r[q], cmax[q]);
        alpha[q] = exp2f(m_r[q] - mn);
        m_r[q] = mn;
        rsum[q] = 0.f;
      }
#pragma unroll
      for (int t = 0; t < 4; ++t)
#pragma unroll
        for (int q = 0; q < 4; ++q) {
          float p = exp2f(sc[t][q] - m_r[q]);
          rsum[q] += p;
          sc[t][q] = p;
        }
#pragma unroll
      for (int q = 0; q < 4; ++q) {
        float v = rsum[q];
        v += __shfl_xor(v, 1);
        v += __shfl_xor(v, 2);
        v += __shfl_xor(v, 4);
        v += __shfl_xor(v, 8);
        l_r[q] = l_r[q] * alpha[q] + v;
      }
#pragma unroll
      for (int dt = 0; dt < 8; ++dt)
#pragma unroll
        for (int q = 0; q < 4; ++q) acc[dt][q] *= alpha[q];
#pragma unroll
      for (int t = 0; t < 4; ++t)
#pragma unroll
        for (int q = 0; q < 4; ++q)
          Ps[w][(lg * 4 + q) * 80 + t * 16 + lr] = f2bf(sc[t][q]);
      __builtin_amdgcn_s_setprio(1);
#pragma unroll
      for (int kc = 0; kc < 2; ++kc) {
        bf16x8 ap = *(const bf16x8*)(&Ps[w][lr * 80 + kc * 32 + lg * 8]);
#pragma unroll
        for (int dt = 0; dt < 8; ++dt) {
          int row = dt * 16 + lr;
          int bo = (row * 128 + kc * 64 + lg * 16) ^ ((row & 7) << 4);
          bf16x8 bv = *(const bf16x8*)(Vc + bo);
          acc[dt] = __builtin_amdgcn_mfma_f32_16x16x32_bf16(ap, bv, acc[dt], 0, 0, 0);
        }
      }
      __builtin_amdgcn_s_setprio(0);
      __syncthreads();
    }

    // ---- epilogue: per-wave 2-chunk staging through Ps, coalesced stores ----
    float inv4[4];
#pragma unroll
    for (int q = 0; q < 4; ++q) inv4[q] = 1.f / l_r[q];
    const int rr = l >> 2, c4 = l & 3;
#pragma unroll
    for (int chv = 0; chv < 2; ++chv) {
#pragma unroll
      for (int q = 0; q < 4; ++q) {
        int rl = lg * 4 + q;
#pragma unroll
        for (int dt = 0; dt < 4; ++dt)
          Ps[w][rl * 80 + dt * 16 + lr] = f2bf(acc[chv * 4 + dt][q] * inv4[q]);
      }
      const unsigned short* srow = &Ps[w][rr * 80 + c4 * 8];
      size_t gb = (size_t)(b * 2048 + q0 + w * 16 + rr) * 2048 + h * 128 + chv * 64 + c4 * 8;
      *(s16x8*)(ctx + gb) = *(const s16x8*)(srow);
      *(s16x8*)(ctx + gb + 32) = *(const s16x8*)(srow + 32);
    }
  }
}

// ---------- launch ----------
extern "C" void kernel_launch(void* const* d_in, const int* in_sizes, int n_in,
                              void* d_out, int out_size, void* d_ws, size_t ws_size,
                              hipStream_t stream) {
  const float* hs   = (const float*)d_in[0];
  const float* ln1g = (const float*)d_in[3];
  const float* ln1b = (const float*)d_in[4];
  const float* wqkv = (const float*)d_in[5];
  const float* bqkv = (const float*)d_in[6];
  const float* wo   = (const float*)d_in[7];
  const float* bo   = (const float*)d_in[8];
  const float* ln2g = (const float*)d_in[9];
  const float* ln2b = (const float*)d_in[10];
  const float* wfc  = (const float*)d_in[11];
  const float* bfc  = (const float*)d_in[12];
  const float* wfc2 = (const float*)d_in[13];
  const float* bfc2 = (const float*)d_in[14];
  const float* wpj  = (const float*)d_in[15];
  const float* bpj  = (const float*)d_in[16];

  char* ws = (char*)d_ws;
  unsigned short* woT   = (unsigned short*)(ws + 0);          //  8 MB
  unsigned short* wfcT  = (unsigned short*)(ws + 8388608);    // 24 MB
  unsigned short* wfc2T = (unsigned short*)(ws + 33554432);   // 24 MB
  unsigned short* hbuf  = (unsigned short*)(ws + 58720256);   // 16 MB
  unsigned short* qkvb  = (unsigned short*)(ws + 75497472);   // 48 MB (later mlp_in)
  unsigned short* wqkvT = (unsigned short*)(ws + 125829120);  // 24 MB (later wpjT)
  unsigned short* vTb   = (unsigned short*)(ws + 150994944);  // 16 MB
  unsigned short* ctxb  = (unsigned short*)(ws + 167772160);  // 16 MB
  unsigned short* wpjT  = wqkvT;
  float* outf = (float*)d_out;

  dim3 blk(256), blk512(512);
  transpose_cast_f32<<<dim3(96, 32), blk, 0, stream>>>(wqkv, wqkvT, 2048, 6144);
  transpose_cast_f32<<<dim3(32, 32), blk, 0, stream>>>(wo, woT, 2048, 2048);
  transpose_cast_f32<<<dim3(96, 32), blk, 0, stream>>>(wfc, wfcT, 2048, 6144);
  transpose_cast_f32<<<dim3(96, 32), blk, 0, stream>>>(wfc2, wfc2T, 2048, 6144);
  ln_kernel<<<dim3(4096), blk, 0, stream>>>(hs, ln1g, ln1b, hbuf);
  // QKV: [4096,2048] x [6144,2048]^T -> [4096,6144] bf16
  gemm256<0><<<dim3(24, 16), blk512, 0, stream>>>(hbuf, 2048, wqkvT, bqkv, nullptr,
                                                  qkvb, 6144, 2048);
  transpose_v<<<dim3(32, 2, 32), blk, 0, stream>>>(qkvb, vTb);
  transpose_cast_f32<<<dim3(32, 96), blk, 0, stream>>>(wpj, wpjT, 6144, 2048);
  // attention (paired q-tiles, K/V double-buffer, XCD-local bh)
  attn_kernel<<<dim3(512), blk, 0, stream>>>(qkvb, vTb, ctxb);
  // O-proj + residual -> d_out f32
  gemm_n128<1, false><<<dim3(16, 16), blk512, 0, stream>>>(
      ctxb, 2048, woT, nullptr, bo, nullptr, hs, d_out, 2048, 2048);
  ln_kernel<<<dim3(4096), blk, 0, stream>>>(outf, ln2g, ln2b, hbuf);
  // fused MLP gate/up: out = (h2@wfc + bfc) * silu(h2@wfc2 + bfc2)
  gemm_mlp<<<dim3(48, 16), blk512, 0, stream>>>(
      hbuf, 2048, wfcT, wfc2T, bfc, bfc2, qkvb, 6144, 2048);
  // proj + residual -> d_out
  gemm_n128<1, false><<<dim3(16, 16), blk512, 0, stream>>>(
      qkvb, 6144, wpjT, nullptr, bpj, nullptr, outf, d_out, 2048, 6144);
}

// Round 9
// 691.314 us; speedup vs baseline: 1.0467x; 1.0352x over previous
//
#include <hip/hip_runtime.h>
#include <hip/hip_bf16.h>
#include <math.h>

#define DI __device__ __forceinline__

typedef __bf16 bf16x8 __attribute__((ext_vector_type(8)));
typedef float f32x4 __attribute__((ext_vector_type(4)));
typedef short s16x8 __attribute__((ext_vector_type(8)));

// ---------- helpers ----------
DI unsigned short f2bf(float f) {
  unsigned int u = __builtin_bit_cast(unsigned int, f);
  unsigned int r = (u + 0x7fffu + ((u >> 16) & 1u)) >> 16;
  return (unsigned short)r;
}
DI float bf2f(unsigned short h) {
  unsigned int u = ((unsigned int)h) << 16;
  return __builtin_bit_cast(float, u);
}

DI void gload16(const void* g, void* l) {
  __builtin_amdgcn_global_load_lds(
      (const __attribute__((address_space(1))) void*)g,
      (__attribute__((address_space(3))) void*)l, 16, 0, 0);
}

DI unsigned ldsoff(const void* p) {
  return (unsigned)(size_t)(const __attribute__((address_space(3))) void*)p;
}

// asm ds_read_b128 with compile-time offset: compiler cannot sink/elide it.
template <int OFF>
DI bf16x8 ds128(unsigned base) {
  bf16x8 r;
  asm volatile("ds_read_b128 %0, %1 offset:%2" : "=v"(r) : "v"(base), "i"(OFF));
  return r;
}
// counted waits + sched_barrier(0) (MFMA intrinsics can hoist past bare
// inline-asm waitcnt; the sched_barrier pins them below).
template <int N>
DI void lgkm() {
  asm volatile("s_waitcnt lgkmcnt(%0)" ::"i"(N));
  __builtin_amdgcn_sched_barrier(0);
}
template <int N>
DI void vmc() {
  asm volatile("s_waitcnt vmcnt(%0)" ::"i"(N));
  __builtin_amdgcn_sched_barrier(0);
}

// 2-D XCD rasterization for GEMMs.
DI void xcd_map(int BN, int& m0, int& n0) {
  const int nx = gridDim.x;
  int orig = blockIdx.y * nx + blockIdx.x;
  int xcd = orig & 7, k = orig >> 3;
  int xm = xcd >> 2, xn = xcd & 3;
  int nband = nx >> 2;
  m0 = (xm * 8 + (k & 7)) * 256;
  n0 = (xn * nband + (k >> 3)) * BN;
}

// ---------- transpose + fp32->bf16 cast ----------
__global__ __launch_bounds__(256)
void transpose_cast_f32(const float* __restrict__ in, unsigned short* __restrict__ out,
                        int R, int C) {
  __shared__ unsigned int t[64 * 65];
  const int r0 = blockIdx.y * 64, c0 = blockIdx.x * 64;
  const int tid = threadIdx.x;
#pragma unroll
  for (int p = 0; p < 4; ++p) {
    int e = p * 1024 + tid * 4;
    int r = e >> 6, c = e & 63;
    float4 v = *(const float4*)(in + (size_t)(r0 + r) * C + c0 + c);
    t[r * 65 + c + 0] = f2bf(v.x);
    t[r * 65 + c + 1] = f2bf(v.y);
    t[r * 65 + c + 2] = f2bf(v.z);
    t[r * 65 + c + 3] = f2bf(v.w);
  }
  __syncthreads();
  const int oc = tid >> 2, ch = tid & 3;
  alignas(16) unsigned short vals[16];
#pragma unroll
  for (int j = 0; j < 16; ++j) vals[j] = (unsigned short)t[(ch * 16 + j) * 65 + oc];
  size_t ob = (size_t)(c0 + oc) * R + r0 + ch * 16;
  *(s16x8*)(out + ob) = *(const s16x8*)(vals);
  *(s16x8*)(out + ob + 8) = *(const s16x8*)(vals + 8);
}

// ---------- V transpose ----------
__global__ __launch_bounds__(256)
void transpose_v(const unsigned short* __restrict__ qkv, unsigned short* __restrict__ vT) {
  __shared__ unsigned int t[64 * 65];
  const int s0 = blockIdx.x * 64, d0 = blockIdx.y * 64, bh = blockIdx.z;
  const int b = bh >> 4, h = bh & 15;
  const int tid = threadIdx.x;
#pragma unroll
  for (int p = 0; p < 2; ++p) {
    int id = p * 256 + tid;
    int r = id >> 3, c = (id & 7) * 8;
    s16x8 v = *(const s16x8*)(qkv + (size_t)(b * 2048 + s0 + r) * 6144 + 4096 + h * 128 + d0 + c);
#pragma unroll
    for (int j = 0; j < 8; ++j) t[r * 65 + c + j] = (unsigned short)((const unsigned short*)&v)[j];
  }
  __syncthreads();
  const int oc = tid >> 2, ch = tid & 3;
  alignas(16) unsigned short vals[16];
#pragma unroll
  for (int j = 0; j < 16; ++j) vals[j] = (unsigned short)t[(ch * 16 + j) * 65 + oc];
  size_t ob = (size_t)(bh * 128 + d0 + oc) * 2048 + s0 + ch * 16;
  *(s16x8*)(vT + ob) = *(const s16x8*)(vals);
  *(s16x8*)(vT + ob + 8) = *(const s16x8*)(vals + 8);
}

// ---------- LayerNorm fp32 -> bf16, row = 2048 ----------
__global__ __launch_bounds__(256)
void ln_kernel(const float* __restrict__ x, const float* __restrict__ g,
               const float* __restrict__ bi, unsigned short* __restrict__ y) {
  __shared__ float red[8];
  const int row = blockIdx.x, tid = threadIdx.x;
  const float* xp = x + (size_t)row * 2048 + tid * 8;
  float4 v0 = *(const float4*)xp;
  float4 v1 = *(const float4*)(xp + 4);
  float v[8] = {v0.x, v0.y, v0.z, v0.w, v1.x, v1.y, v1.z, v1.w};
  float s = 0.f;
#pragma unroll
  for (int j = 0; j < 8; ++j) s += v[j];
#pragma unroll
  for (int d = 1; d < 64; d <<= 1) s += __shfl_xor(s, d);
  if ((tid & 63) == 0) red[tid >> 6] = s;
  __syncthreads();
  float mean = (red[0] + red[1] + red[2] + red[3]) * (1.f / 2048.f);
  float dd[8], sq = 0.f;
#pragma unroll
  for (int j = 0; j < 8; ++j) { dd[j] = v[j] - mean; sq += dd[j] * dd[j]; }
#pragma unroll
  for (int d = 1; d < 64; d <<= 1) sq += __shfl_xor(sq, d);
  if ((tid & 63) == 0) red[4 + (tid >> 6)] = sq;
  __syncthreads();
  float var = (red[4] + red[5] + red[6] + red[7]) * (1.f / 2048.f);
  float rs = rsqrtf(var + 1e-5f);
  float4 g0 = *(const float4*)(g + tid * 8), g1 = *(const float4*)(g + tid * 8 + 4);
  float4 b0 = *(const float4*)(bi + tid * 8), b1 = *(const float4*)(bi + tid * 8 + 4);
  float gg[8] = {g0.x, g0.y, g0.z, g0.w, g1.x, g1.y, g1.z, g1.w};
  float bb[8] = {b0.x, b0.y, b0.z, b0.w, b1.x, b1.y, b1.z, b1.w};
  alignas(16) unsigned short o[8];
#pragma unroll
  for (int j = 0; j < 8; ++j) o[j] = f2bf(dd[j] * rs * gg[j] + bb[j]);
  *(s16x8*)(y + (size_t)row * 2048 + tid * 8) = *(const s16x8*)o;
}

// ---------- shared GEMM staging ----------
DI void stage_half(const unsigned short* __restrict__ G, int ld, int rbase, int kt,
                   int h, unsigned short* dst, int tid) {
#pragma unroll
  for (int i = 0; i < 2; ++i) {
    int id = i * 512 + tid;
    int rl = id >> 3, sl = id & 7;
    int ss = sl ^ (rl & 7);
    gload16(G + (size_t)(rbase + h * 128 + rl) * ld + kt + ss * 8,
            (char*)dst + h * 16384 + id * 16);
  }
}

#define RDA(dst, B0_, B1_, OFS)                                        \
  dst[0][0] = ds128<(OFS) + 0>(B0_);    dst[0][1] = ds128<(OFS) + 0>(B1_);    \
  dst[1][0] = ds128<(OFS) + 2048>(B0_); dst[1][1] = ds128<(OFS) + 2048>(B1_); \
  dst[2][0] = ds128<(OFS) + 4096>(B0_); dst[2][1] = ds128<(OFS) + 4096>(B1_); \
  dst[3][0] = ds128<(OFS) + 6144>(B0_); dst[3][1] = ds128<(OFS) + 6144>(B1_);

#define RDB(dst, B0_, B1_, OFS)                                        \
  dst[0][0] = ds128<(OFS) + 0>(B0_);    dst[0][1] = ds128<(OFS) + 0>(B1_);    \
  dst[1][0] = ds128<(OFS) + 2048>(B0_); dst[1][1] = ds128<(OFS) + 2048>(B1_);

// ---------- 256x256 GEMM (QKV): counted-asm + cross-iter pre-issue ---------
// gemm_mlp-style: a0+b01 of tile t+1 are issued during t's c4 (drain under Q4
// and the c4 barrier) instead of at t+1's c1 head. Safety: the wait that
// guarantees tile t+1 landed CU-wide moved from c4 to c3 (vmc<2> leaves only
// Bh0(t+2) in flight; c3-end barrier publishes) - the c4 pre-issue reads
// therefore follow [all-waves drain of tile t+1] + barrier. Stage placement
// unchanged; lgkm counts at c1/c2/c3 unchanged (pre-issued reads are oldest
// in the per-wave LDS FIFO).
// MODE 0: out bf16 = acc + bias ; MODE 1: out f32 = acc + bias + res
template <int MODE>
__global__ __launch_bounds__(512, 2)
void gemm256(const unsigned short* __restrict__ A, int lda,
             const unsigned short* __restrict__ B,
             const float* __restrict__ bias,
             const void* __restrict__ resg,
             void* __restrict__ out, int ldc, int K) {
  __shared__ alignas(16) unsigned short As[2][256 * 64];
  __shared__ alignas(16) unsigned short Bs[2][256 * 64];

  const int tid = threadIdx.x;
  const int l = tid & 63, w = tid >> 6;
  const int wr = w >> 2, wc = w & 3;
  const int lr = l & 15, lg = l >> 4;

  int m0, n0;
  xcd_map(256, m0, n0);

  const int NT = K >> 6;

  f32x4 acc[8][4];
  const f32x4 z4 = {0.f, 0.f, 0.f, 0.f};
#pragma unroll
  for (int i = 0; i < 8; ++i)
#pragma unroll
    for (int j = 0; j < 4; ++j) acc[i][j] = z4;

  const int s7 = lr & 7;
  const unsigned swz0 = (unsigned)((lg ^ s7) << 4);
  const unsigned swz1 = (unsigned)(((4 | lg) ^ s7) << 4);
  const unsigned rA = (unsigned)((wr * 128 + lr) * 128);
  const unsigned rB = (unsigned)((wc * 64 + lr) * 128);
  const unsigned aA0 = ldsoff(&As[0][0]) + rA + swz0;
  const unsigned aA1 = ldsoff(&As[0][0]) + rA + swz1;
  const unsigned bA0 = ldsoff(&Bs[0][0]) + rB + swz0;
  const unsigned bA1 = ldsoff(&Bs[0][0]) + rB + swz1;

  stage_half(A, lda, m0, 0, 0, As[0], tid);
  stage_half(A, lda, m0, 0, 1, As[0], tid);
  stage_half(B, K, n0, 0, 0, Bs[0], tid);
  stage_half(B, K, n0, 0, 1, Bs[0], tid);
  if (NT > 1) {
    stage_half(B, K, n0, 64, 0, Bs[1], tid);
    stage_half(B, K, n0, 64, 1, Bs[1], tid);
    stage_half(A, lda, m0, 64, 0, As[1], tid);
    asm volatile("s_waitcnt vmcnt(6)" ::: "memory");
  } else {
    asm volatile("s_waitcnt vmcnt(0)" ::: "memory");
  }
  __builtin_amdgcn_s_barrier();

  bf16x8 a0[4][2], a1[4][2], bfr[4][2];
  // pre-issue tile0's a0(8)+b01(4) (tile0 landed + barrier above)
#pragma unroll
  for (int i = 0; i < 4; ++i) {
    a0[i][0] = ds128<0>(aA0 + i * 2048);
    a0[i][1] = ds128<0>(aA1 + i * 2048);
  }
#pragma unroll
  for (int j = 0; j < 2; ++j) {
    bfr[j][0] = ds128<0>(bA0 + j * 2048);
    bfr[j][1] = ds128<0>(bA1 + j * 2048);
  }

  for (int t = 0; t < NT; ++t) {
    const unsigned co = (unsigned)((t & 1) * 32768);
    const unsigned a0b = aA0 + co, a1b = aA1 + co;
    const unsigned b0b = bA0 + co, b1b = bA1 + co;

    // ---- c1: issue b23(4); stage Ah1(t+1); lgkm<4> (a0+b01 pre-issued);
    //      Q1 = a0 x b01 (b23 drains underneath) ----
#pragma unroll
    for (int j = 2; j < 4; ++j) {
      bfr[j][0] = ds128<0>(b0b + j * 2048);
      bfr[j][1] = ds128<0>(b1b + j * 2048);
    }
    if (t + 1 < NT) stage_half(A, lda, m0, (t + 1) * 64, 1, As[(t & 1) ^ 1], tid);
    lgkm<4>();
    __builtin_amdgcn_s_setprio(1);
#pragma unroll
    for (int i = 0; i < 4; ++i)
#pragma unroll
      for (int j = 0; j < 2; ++j)
#pragma unroll
        for (int kk = 0; kk < 2; ++kk)
          acc[i][j] = __builtin_amdgcn_mfma_f32_16x16x32_bf16(a0[i][kk], bfr[j][kk], acc[i][j], 0, 0, 0);
    __builtin_amdgcn_s_setprio(0);
    __builtin_amdgcn_s_barrier();

    // ---- c2: issue a1(8); lgkm<8> (drains b23); Q2 = a0 x b23 ----
#pragma unroll
    for (int i = 0; i < 4; ++i) {
      a1[i][0] = ds128<8192>(a0b + i * 2048);
      a1[i][1] = ds128<8192>(a1b + i * 2048);
    }
    lgkm<8>();
    __builtin_amdgcn_s_setprio(1);
#pragma unroll
    for (int i = 0; i < 4; ++i)
#pragma unroll
      for (int j = 2; j < 4; ++j)
#pragma unroll
        for (int kk = 0; kk < 2; ++kk)
          acc[i][j] = __builtin_amdgcn_mfma_f32_16x16x32_bf16(a0[i][kk], bfr[j][kk], acc[i][j], 0, 0, 0);
    __builtin_amdgcn_s_setprio(0);
    __builtin_amdgcn_s_barrier();

    // ---- c3: stage Bh0(t+2); lgkm<0> (drains a1); Q3 = a1 x b01;
    //      vmc<2> drains tile t+1 (leaves Bh0(t+2)); barrier publishes ----
    if (t + 2 < NT) stage_half(B, K, n0, (t + 2) * 64, 0, Bs[t & 1], tid);
    lgkm<0>();
    __builtin_amdgcn_s_setprio(1);
#pragma unroll
    for (int i = 0; i < 4; ++i)
#pragma unroll
      for (int j = 0; j < 2; ++j)
#pragma unroll
        for (int kk = 0; kk < 2; ++kk)
          acc[i + 4][j] = __builtin_amdgcn_mfma_f32_16x16x32_bf16(a1[i][kk], bfr[j][kk], acc[i + 4][j], 0, 0, 0);
    __builtin_amdgcn_s_setprio(0);
    if (t + 2 < NT) { vmc<2>(); } else { vmc<0>(); }
    __builtin_amdgcn_s_barrier();

    // ---- c4: stage Bh1+Ah0(t+2); pre-issue a0/b01(t+1); Q4 = a1 x b23 ----
    if (t + 2 < NT) {
      stage_half(B, K, n0, (t + 2) * 64, 1, Bs[t & 1], tid);
      stage_half(A, lda, m0, (t + 2) * 64, 0, As[t & 1], tid);
    }
    if (t + 1 < NT) {
      const unsigned nco = (unsigned)(((t + 1) & 1) * 32768);
      const unsigned na0 = aA0 + nco, na1 = aA1 + nco;
      const unsigned nb0 = bA0 + nco, nb1 = bA1 + nco;
#pragma unroll
      for (int i = 0; i < 4; ++i) {
        a0[i][0] = ds128<0>(na0 + i * 2048);
        a0[i][1] = ds128<0>(na1 + i * 2048);
      }
#pragma unroll
      for (int j = 0; j < 2; ++j) {
        bfr[j][0] = ds128<0>(nb0 + j * 2048);
        bfr[j][1] = ds128<0>(nb1 + j * 2048);
      }
    }
    __builtin_amdgcn_s_setprio(1);
#pragma unroll
    for (int i = 0; i < 4; ++i)
#pragma unroll
      for (int j = 2; j < 4; ++j)
#pragma unroll
        for (int kk = 0; kk < 2; ++kk)
          acc[i + 4][j] = __builtin_amdgcn_mfma_f32_16x16x32_bf16(a1[i][kk], bfr[j][kk], acc[i + 4][j], 0, 0, 0);
    __builtin_amdgcn_s_setprio(0);
    __builtin_amdgcn_s_barrier();
  }

#pragma unroll
  for (int i = 0; i < 8; ++i) {
    int r0 = m0 + wr * 128 + i * 16 + lg * 4;
#pragma unroll
    for (int j = 0; j < 4; ++j) {
      int col = n0 + wc * 64 + j * 16 + lr;
      float bb = bias[col];
#pragma unroll
      for (int q = 0; q < 4; ++q) {
        size_t off = (size_t)(r0 + q) * ldc + col;
        float v = acc[i][j][q] + bb;
        if (MODE == 0) {
          ((unsigned short*)out)[off] = f2bf(v);
        } else {
          ((float*)out)[off] = v + ((const float*)resg)[off];
        }
      }
    }
  }
}

// ---------- 256x128 GEMM single-B (O-proj / proj): counted-asm 2-cluster ----
// (r4-verified, unchanged)
template <int MODE, bool DUAL>
__global__ __launch_bounds__(512, 2)
void gemm_n128(const unsigned short* __restrict__ A, int lda,
               const unsigned short* __restrict__ B0,
               const unsigned short* __restrict__ B1,
               const float* __restrict__ bias0, const float* __restrict__ bias1,
               const void* __restrict__ resg,
               void* __restrict__ out, int ldc, int K) {
  __shared__ alignas(16) unsigned short As[2][256 * 64];
  __shared__ alignas(16) unsigned short Bs0[2][128 * 64];

  const int tid = threadIdx.x;
  const int l = tid & 63, w = tid >> 6;
  const int wr = w >> 2, wc = w & 3;
  const int lr = l & 15, lg = l >> 4;

  int m0, n0;
  xcd_map(128, m0, n0);

  const int NT = K >> 6;

  f32x4 acc0[8][2];
  const f32x4 z4 = {0.f, 0.f, 0.f, 0.f};
#pragma unroll
  for (int i = 0; i < 8; ++i)
#pragma unroll
    for (int j = 0; j < 2; ++j) acc0[i][j] = z4;

  const int s7 = lr & 7;
  const unsigned swz0 = (unsigned)((lg ^ s7) << 4);
  const unsigned swz1 = (unsigned)(((4 | lg) ^ s7) << 4);
  const unsigned rA = (unsigned)((wr * 128 + lr) * 128);
  const unsigned rB = (unsigned)((wc * 32 + lr) * 128);
  const unsigned aA0 = ldsoff(&As[0][0]) + rA + swz0;
  const unsigned aA1 = ldsoff(&As[0][0]) + rA + swz1;
  const unsigned bA0 = ldsoff(&Bs0[0][0]) + rB + swz0;
  const unsigned bA1 = ldsoff(&Bs0[0][0]) + rB + swz1;

  // prologue
  stage_half(A, lda, m0, 0, 0, As[0], tid);
  stage_half(A, lda, m0, 0, 1, As[0], tid);
  stage_half(B0, K, n0, 0, 0, Bs0[0], tid);
  if (NT > 1) {
    stage_half(B0, K, n0, 64, 0, Bs0[1], tid);
    stage_half(A, lda, m0, 64, 0, As[1], tid);
    asm volatile("s_waitcnt vmcnt(4)" ::: "memory");
  } else {
    asm volatile("s_waitcnt vmcnt(0)" ::: "memory");
  }
  __builtin_amdgcn_s_barrier();

  for (int t = 0; t < NT; ++t) {
    const int cur = t & 1;
    const unsigned ca = aA0 + (unsigned)(cur * 32768);
    const unsigned ca1 = aA1 + (unsigned)(cur * 32768);
    const unsigned cb = bA0 + (unsigned)(cur * 16384);
    const unsigned cb1 = bA1 + (unsigned)(cur * 16384);
    bf16x8 a0[4][2], a1[4][2], b0f[2][2];

    // ---- c1: issue a0(8)+b0(4); stage Ah1(t+1); issue a1(8); lgkm<8>;
    //      Q1 = a0 x b0 (a1 drains underneath) ----
#pragma unroll
    for (int i = 0; i < 4; ++i) {
      a0[i][0] = ds128<0>(ca + i * 2048);
      a0[i][1] = ds128<0>(ca1 + i * 2048);
    }
#pragma unroll
    for (int j = 0; j < 2; ++j) {
      b0f[j][0] = ds128<0>(cb + j * 2048);
      b0f[j][1] = ds128<0>(cb1 + j * 2048);
    }
    if (t + 1 < NT) stage_half(A, lda, m0, (t + 1) * 64, 1, As[cur ^ 1], tid);
#pragma unroll
    for (int i = 0; i < 4; ++i) {
      a1[i][0] = ds128<8192>(ca + i * 2048);
      a1[i][1] = ds128<8192>(ca1 + i * 2048);
    }
    lgkm<8>();
    __builtin_amdgcn_s_setprio(1);
#pragma unroll
    for (int i = 0; i < 4; ++i)
#pragma unroll
      for (int j = 0; j < 2; ++j)
#pragma unroll
        for (int kk = 0; kk < 2; ++kk)
          acc0[i][j] = __builtin_amdgcn_mfma_f32_16x16x32_bf16(a0[i][kk], b0f[j][kk], acc0[i][j], 0, 0, 0);
    __builtin_amdgcn_s_setprio(0);
    __builtin_amdgcn_s_barrier();

    // ---- c2: stage B0(t+2); lgkm<0> (drain a1); stage Ah0(t+2); Q2 ----
    if (t + 2 < NT) stage_half(B0, K, n0, (t + 2) * 64, 0, Bs0[cur], tid);
    lgkm<0>();
    if (t + 2 < NT) stage_half(A, lda, m0, (t + 2) * 64, 0, As[cur], tid);
    __builtin_amdgcn_s_setprio(1);
#pragma unroll
    for (int i = 0; i < 4; ++i)
#pragma unroll
      for (int j = 0; j < 2; ++j)
#pragma unroll
        for (int kk = 0; kk < 2; ++kk)
          acc0[i + 4][j] = __builtin_amdgcn_mfma_f32_16x16x32_bf16(a1[i][kk], b0f[j][kk], acc0[i + 4][j], 0, 0, 0);
    __builtin_amdgcn_s_setprio(0);
    if (t + 2 < NT) { vmc<4>(); } else { vmc<0>(); }
    __builtin_amdgcn_s_barrier();
  }

  // epilogue
#pragma unroll
  for (int i = 0; i < 8; ++i) {
    int r0 = m0 + wr * 128 + i * 16 + lg * 4;
#pragma unroll
    for (int j = 0; j < 2; ++j) {
      int col = n0 + wc * 32 + j * 16 + lr;
      float bb0 = bias0[col];
#pragma unroll
      for (int q = 0; q < 4; ++q) {
        size_t off = (size_t)(r0 + q) * ldc + col;
        float v = acc0[i][j][q] + bb0;
        ((float*)out)[off] = v + ((const float*)resg)[off];
      }
    }
  }
}

// ---------- MLP dual GEMM: 256x128, counted-wait asm-pipelined 4-phase ------
// (r2/r4-verified schedule, unchanged)
DI void mmq(f32x4 (&acc)[8][2], int io, const bf16x8 (&af)[4][2], const bf16x8 (&bf)[2][2]) {
#pragma unroll
  for (int kk = 0; kk < 2; ++kk)
#pragma unroll
    for (int i = 0; i < 4; ++i)
#pragma unroll
      for (int j = 0; j < 2; ++j)
        acc[io + i][j] = __builtin_amdgcn_mfma_f32_16x16x32_bf16(af[i][kk], bf[j][kk], acc[io + i][j], 0, 0, 0);
}

#define MLP_ITER(t, CUR, A0C, B0C, B1C, A1C, A0N, B0N)                         \
  {                                                                            \
    /* P1: issue b1(t); wait a0(t),b0(t); Q1 = a0 x b0 -> acc0 lo */           \
    RDB(B1C, cA0, cA1, (CUR) * 16384);                                         \
    lgkm<4>();                                                                 \
    __builtin_amdgcn_s_setprio(1);                                             \
    mmq(acc0, 0, A0C, B0C);                                                    \
    __builtin_amdgcn_s_setprio(0);                                             \
    __builtin_amdgcn_sched_barrier(0);                                         \
    __builtin_amdgcn_s_barrier();                                              \
    /* P2: stage B0(t+2); issue a1(t); wait b1(t); Q2 = a0 x b1 -> acc1 lo */  \
    if ((t) + 2 < NT) stage_half(B0, K, n0, ((t) + 2) * 64, 0, Bs0[CUR], tid); \
    RDA(A1C, aA0, aA1, (CUR) * 32768 + 8192);                                  \
    lgkm<8>();                                                                 \
    __builtin_amdgcn_s_setprio(1);                                             \
    mmq(acc1, 0, A0C, B1C);                                                    \
    __builtin_amdgcn_s_setprio(0);                                             \
    if ((t) + 2 < NT) { vmc<2>(); } else { vmc<0>(); }                         \
    __builtin_amdgcn_s_barrier();                                              \
    /* P3: stage B1(t+2); issue a0(t+1); wait a1(t); Q3 = a1 x b0 -> acc0 hi */\
    if ((t) + 2 < NT) stage_half(B1, K, n0, ((t) + 2) * 64, 0, Bs1[CUR], tid); \
    RDA(A0N, aA0, aA1, ((CUR) ^ 1) * 32768);                                   \
    lgkm<8>();                                                                 \
    __builtin_amdgcn_s_setprio(1);                                             \
    mmq(acc0, 4, A1C, B0C);                                                    \
    __builtin_amdgcn_s_setprio(0);                                             \
    __builtin_amdgcn_sched_barrier(0);                                         \
    __builtin_amdgcn_s_barrier();                                              \
    /* P4: stage A(t+2) both halves; issue b0(t+1); Q4 = a1 x b1 -> acc1 hi */ \
    if ((t) + 2 < NT) {                                                        \
      stage_half(A, lda, m0, ((t) + 2) * 64, 0, As[CUR], tid);                 \
      stage_half(A, lda, m0, ((t) + 2) * 64, 1, As[CUR], tid);                 \
    }                                                                          \
    RDB(B0N, bA0, bA1, ((CUR) ^ 1) * 16384);                                   \
    __builtin_amdgcn_sched_barrier(0);                                         \
    __builtin_amdgcn_s_setprio(1);                                             \
    mmq(acc1, 4, A1C, B1C);                                                    \
    __builtin_amdgcn_s_setprio(0);                                             \
    __builtin_amdgcn_sched_barrier(0);                                         \
    __builtin_amdgcn_s_barrier();                                              \
  }

__global__ __launch_bounds__(512, 2)
void gemm_mlp(const unsigned short* __restrict__ A, int lda,
              const unsigned short* __restrict__ B0,
              const unsigned short* __restrict__ B1,
              const float* __restrict__ bias0, const float* __restrict__ bias1,
              unsigned short* __restrict__ out, int ldc, int K) {
  __shared__ alignas(16) unsigned short As[2][256 * 64];
  __shared__ alignas(16) unsigned short Bs0[2][128 * 64];
  __shared__ alignas(16) unsigned short Bs1[2][128 * 64];

  const int tid = threadIdx.x;
  const int l = tid & 63, w = tid >> 6;
  const int wr = w >> 2, wc = w & 3;
  const int lr = l & 15, lg = l >> 4;

  int m0, n0;
  xcd_map(128, m0, n0);
  const int NT = K >> 6;  // even (K=2048 -> 32)

  f32x4 acc0[8][2], acc1[8][2];
  const f32x4 z4 = {0.f, 0.f, 0.f, 0.f};
#pragma unroll
  for (int i = 0; i < 8; ++i)
#pragma unroll
    for (int j = 0; j < 2; ++j) { acc0[i][j] = z4; acc1[i][j] = z4; }

  const int s7 = lr & 7;
  const unsigned swz0 = (unsigned)((lg ^ s7) << 4);
  const unsigned swz1 = (unsigned)(((4 | lg) ^ s7) << 4);
  const unsigned rA = (unsigned)((wr * 128 + lr) * 128);
  const unsigned rB = (unsigned)((wc * 32 + lr) * 128);
  const unsigned aA0 = ldsoff(&As[0][0]) + rA + swz0;
  const unsigned aA1 = ldsoff(&As[0][0]) + rA + swz1;
  const unsigned bA0 = ldsoff(&Bs0[0][0]) + rB + swz0;
  const unsigned bA1 = ldsoff(&Bs0[0][0]) + rB + swz1;
  const unsigned cA0 = ldsoff(&Bs1[0][0]) + rB + swz0;
  const unsigned cA1 = ldsoff(&Bs1[0][0]) + rB + swz1;

  bf16x8 a0X[4][2], a1X[4][2], b0X[2][2], b1X[2][2];
  bf16x8 a0Y[4][2], a1Y[4][2], b0Y[2][2], b1Y[2][2];

  stage_half(A, lda, m0, 0, 0, As[0], tid);
  stage_half(A, lda, m0, 0, 1, As[0], tid);
  stage_half(B0, K, n0, 0, 0, Bs0[0], tid);
  stage_half(B1, K, n0, 0, 0, Bs1[0], tid);
  stage_half(B0, K, n0, 64, 0, Bs0[1], tid);
  stage_half(B1, K, n0, 64, 0, Bs1[1], tid);
  stage_half(A, lda, m0, 64, 0, As[1], tid);
  stage_half(A, lda, m0, 64, 1, As[1], tid);
  vmc<8>();
  __builtin_amdgcn_s_barrier();
  RDA(a0X, aA0, aA1, 0);
  RDB(b0X, bA0, bA1, 0);

  for (int t = 0; t < NT; t += 2) {
    MLP_ITER(t, 0, a0X, b0X, b1X, a1X, a0Y, b0Y);
    MLP_ITER(t + 1, 1, a0Y, b0Y, b1Y, a1Y, a0X, b0X);
  }

  // epilogue: out bf16 = (acc0+bias0) * silu(acc1+bias1)
#pragma unroll
  for (int i = 0; i < 8; ++i) {
    int r0 = m0 + wr * 128 + i * 16 + lg * 4;
#pragma unroll
    for (int j = 0; j < 2; ++j) {
      int col = n0 + wc * 32 + j * 16 + lr;
      float bb0 = bias0[col];
      float bb1 = bias1[col];
#pragma unroll
      for (int q = 0; q < 4; ++q) {
        size_t off = (size_t)(r0 + q) * ldc + col;
        float v = acc0[i][j][q] + bb0;
        float gt = acc1[i][j][q] + bb1;
        out[off] = f2bf(v * (gt / (1.f + expf(-gt))));
      }
    }
  }
}

// ---------- flash attention: paired q-tiles, XCD-local bh, coalesced out ----
// (r4-verified version, restored verbatim: single K/V buffer, 2 barriers/iter,
// Ob epilogue. Both restructurings - r7 q-tile split (+33us) and r8 K/V
// double-buffer (+25us) - regressed; this is the measured local optimum.)
__global__ __launch_bounds__(256, 2)
void attn_kernel(const unsigned short* __restrict__ qkv,
                 const unsigned short* __restrict__ vT,
                 unsigned short* __restrict__ ctx) {
  __shared__ unsigned short Ks[64 * 128];
  __shared__ unsigned short Vs[128 * 64];
  __shared__ unsigned short Ps[4][16 * 80];
  __shared__ unsigned short Ob[4][16 * 136];

  const int g = blockIdx.x;
  const int xcd = g & 7, slot = g >> 3;
  const int bh = xcd * 4 + (slot & 3);
  const int pid = slot >> 2;
  const int b = bh >> 4, h = bh & 15;
  const int tid = threadIdx.x, l = tid & 63, w = tid >> 6;
  const int lr = l & 15, lg = l >> 4;
  const float slope2 = exp2f(-0.5f * (float)(h + 1)) * 1.44269504f;
  const float SC2 = 0.0078125f * 1.44269504f;

  const int krow = tid >> 4, kcb = tid & 15;
  const int vrow = tid >> 3, vcb = tid & 7;
  const unsigned short* kbase = qkv + (size_t)(b * 2048 + krow) * 6144 + 2048 + h * 128 + kcb * 8;
  const unsigned short* vbase = vT + (size_t)(bh * 128 + vrow) * 2048 + vcb * 8;
  char* kdst = (char*)Ks + krow * 256 + ((kcb ^ (krow & 7)) << 4);
  char* vdst = (char*)Vs + vrow * 128 + ((vcb ^ (vrow & 7)) << 4);

  int4 kr[4], vr[4];
#pragma unroll
  for (int p = 0; p < 4; ++p) {
    kr[p] = *(const int4*)(kbase + (size_t)p * 16 * 6144);
    vr[p] = *(const int4*)(vbase + (size_t)p * 32 * 2048);
  }

  for (int tq = 0; tq < 2; ++tq) {
    const int qb = tq ? (31 - pid) : pid;
    const int q0 = qb * 64;
    bf16x8 aq[4];
    {
      const unsigned short* qp =
          qkv + (size_t)(b * 2048 + q0 + w * 16 + lr) * 6144 + h * 128 + lg * 8;
#pragma unroll
      for (int kk = 0; kk < 4; ++kk) aq[kk] = *(const bf16x8*)(qp + kk * 32);
    }
    const f32x4 z4 = {0.f, 0.f, 0.f, 0.f};
    f32x4 acc[8];
#pragma unroll
    for (int dt = 0; dt < 8; ++dt) acc[dt] = z4;
    float m_r[4] = {-INFINITY, -INFINITY, -INFINITY, -INFINITY};
    float l_r[4] = {0.f, 0.f, 0.f, 0.f};
    const int ibase = q0 + w * 16 + lg * 4;
    const int nc = qb + 1;

    for (int c = 0; c < nc; ++c) {
      const int kv0 = c * 64;
      __syncthreads();
#pragma unroll
      for (int p = 0; p < 4; ++p) {
        *(int4*)(kdst + p * 4096) = kr[p];
        *(int4*)(vdst + p * 4096) = vr[p];
      }
      __syncthreads();
      {
        int nxt = (c + 1 < nc) ? (c + 1) * 64 : (tq == 0 ? 0 : -1);
        if (nxt >= 0) {
#pragma unroll
          for (int p = 0; p < 4; ++p) {
            kr[p] = *(const int4*)(kbase + (size_t)nxt * 6144 + (size_t)p * 16 * 6144);
            vr[p] = *(const int4*)(vbase + nxt + (size_t)p * 32 * 2048);
          }
        }
      }

      f32x4 sc[4];
#pragma unroll
      for (int t = 0; t < 4; ++t) sc[t] = z4;
      __builtin_amdgcn_s_setprio(1);
#pragma unroll
      for (int t = 0; t < 4; ++t) {
#pragma unroll
        for (int kk = 0; kk < 4; ++kk) {
          int row = t * 16 + lr;
          int bo = (row * 256 + kk * 64 + lg * 16) ^ ((row & 7) << 4);
          bf16x8 bk = *(const bf16x8*)((const char*)Ks + bo);
          sc[t] = __builtin_amdgcn_mfma_f32_16x16x32_bf16(aq[kk], bk, sc[t], 0, 0, 0);
        }
      }
      __builtin_amdgcn_s_setprio(0);
      float cmax[4] = {-INFINITY, -INFINITY, -INFINITY, -INFINITY};
#pragma unroll
      for (int t = 0; t < 4; ++t)
#pragma unroll
        for (int q = 0; q < 4; ++q) {
          int j = kv0 + t * 16 + lr;
          int i = ibase + q;
          float s = sc[t][q] * SC2 + slope2 * (float)(j - i);
          if (j > i) s = -1e9f;
          sc[t][q] = s;
          cmax[q] = fmaxf(cmax[q], s);
        }
#pragma unroll
      for (int q = 0; q < 4; ++q) {
        float v = cmax[q];
        v = fmaxf(v, __shfl_xor(v, 1));
        v = fmaxf(v, __shfl_xor(v, 2));
        v = fmaxf(v, __shfl_xor(v, 4));
        v = fmaxf(v, __shfl_xor(v, 8));
        cmax[q] = v;
      }
      float alpha[4], rsum[4];
#pragma unroll
      for (int q = 0; q < 4; ++q) {
        float mn = fmaxf(m_r[q], cmax[q]);
        alpha[q] = exp2f(m_r[q] - mn);
        m_r[q] = mn;
        rsum[q] = 0.f;
      }
#pragma unroll
      for (int t = 0; t < 4; ++t)
#pragma unroll
        for (int q = 0; q < 4; ++q) {
          float p = exp2f(sc[t][q] - m_r[q]);
          rsum[q] += p;
          sc[t][q] = p;
        }
#pragma unroll
      for (int q = 0; q < 4; ++q) {
        float v = rsum[q];
        v += __shfl_xor(v, 1);
        v += __shfl_xor(v, 2);
        v += __shfl_xor(v, 4);
        v += __shfl_xor(v, 8);
        l_r[q] = l_r[q] * alpha[q] + v;
      }
#pragma unroll
      for (int dt = 0; dt < 8; ++dt)
#pragma unroll
        for (int q = 0; q < 4; ++q) acc[dt][q] *= alpha[q];
#pragma unroll
      for (int t = 0; t < 4; ++t)
#pragma unroll
        for (int q = 0; q < 4; ++q)
          Ps[w][(lg * 4 + q) * 80 + t * 16 + lr] = f2bf(sc[t][q]);
      __builtin_amdgcn_s_setprio(1);
#pragma unroll
      for (int kc = 0; kc < 2; ++kc) {
        bf16x8 ap = *(const bf16x8*)(&Ps[w][lr * 80 + kc * 32 + lg * 8]);
#pragma unroll
        for (int dt = 0; dt < 8; ++dt) {
          int row = dt * 16 + lr;
          int bo = (row * 128 + kc * 64 + lg * 16) ^ ((row & 7) << 4);
          bf16x8 bv = *(const bf16x8*)((const char*)Vs + bo);
          acc[dt] = __builtin_amdgcn_mfma_f32_16x16x32_bf16(ap, bv, acc[dt], 0, 0, 0);
        }
      }
      __builtin_amdgcn_s_setprio(0);
    }

    // ---- coalesced epilogue: wave-private LDS transpose, 64B-sector stores --
    unsigned short* Kw = &Ob[w][0];
#pragma unroll
    for (int q = 0; q < 4; ++q) {
      float inv = 1.f / l_r[q];
      int rl = lg * 4 + q;
#pragma unroll
      for (int dt = 0; dt < 8; ++dt)
        Kw[rl * 136 + dt * 16 + lr] = f2bf(acc[dt][q] * inv);
    }
    const int rr = l >> 2, c4 = l & 3;
    const unsigned short* srow = Kw + rr * 136 + c4 * 8;
    size_t gb = (size_t)(b * 2048 + q0 + w * 16 + rr) * 2048 + h * 128 + c4 * 8;
#pragma unroll
    for (int k = 0; k < 4; ++k)
      *(s16x8*)(ctx + gb + k * 32) = *(const s16x8*)(srow + k * 32);
  }
}

// ---------- launch ----------
extern "C" void kernel_launch(void* const* d_in, const int* in_sizes, int n_in,
                              void* d_out, int out_size, void* d_ws, size_t ws_size,
                              hipStream_t stream) {
  const float* hs   = (const float*)d_in[0];
  const float* ln1g = (const float*)d_in[3];
  const float* ln1b = (const float*)d_in[4];
  const float* wqkv = (const float*)d_in[5];
  const float* bqkv = (const float*)d_in[6];
  const float* wo   = (const float*)d_in[7];
  const float* bo   = (const float*)d_in[8];
  const float* ln2g = (const float*)d_in[9];
  const float* ln2b = (const float*)d_in[10];
  const float* wfc  = (const float*)d_in[11];
  const float* bfc  = (const float*)d_in[12];
  const float* wfc2 = (const float*)d_in[13];
  const float* bfc2 = (const float*)d_in[14];
  const float* wpj  = (const float*)d_in[15];
  const float* bpj  = (const float*)d_in[16];

  char* ws = (char*)d_ws;
  unsigned short* woT   = (unsigned short*)(ws + 0);          //  8 MB
  unsigned short* wfcT  = (unsigned short*)(ws + 8388608);    // 24 MB
  unsigned short* wfc2T = (unsigned short*)(ws + 33554432);   // 24 MB
  unsigned short* hbuf  = (unsigned short*)(ws + 58720256);   // 16 MB
  unsigned short* qkvb  = (unsigned short*)(ws + 75497472);   // 48 MB (later mlp_in)
  unsigned short* wqkvT = (unsigned short*)(ws + 125829120);  // 24 MB (later wpjT)
  unsigned short* vTb   = (unsigned short*)(ws + 150994944);  // 16 MB
  unsigned short* ctxb  = (unsigned short*)(ws + 167772160);  // 16 MB
  unsigned short* wpjT  = wqkvT;
  float* outf = (float*)d_out;

  dim3 blk(256), blk512(512);
  transpose_cast_f32<<<dim3(96, 32), blk, 0, stream>>>(wqkv, wqkvT, 2048, 6144);
  transpose_cast_f32<<<dim3(32, 32), blk, 0, stream>>>(wo, woT, 2048, 2048);
  transpose_cast_f32<<<dim3(96, 32), blk, 0, stream>>>(wfc, wfcT, 2048, 6144);
  transpose_cast_f32<<<dim3(96, 32), blk, 0, stream>>>(wfc2, wfc2T, 2048, 6144);
  ln_kernel<<<dim3(4096), blk, 0, stream>>>(hs, ln1g, ln1b, hbuf);
  // QKV: [4096,2048] x [6144,2048]^T -> [4096,6144] bf16
  gemm256<0><<<dim3(24, 16), blk512, 0, stream>>>(hbuf, 2048, wqkvT, bqkv, nullptr,
                                                  qkvb, 6144, 2048);
  transpose_v<<<dim3(32, 2, 32), blk, 0, stream>>>(qkvb, vTb);
  transpose_cast_f32<<<dim3(32, 96), blk, 0, stream>>>(wpj, wpjT, 6144, 2048);
  // attention (paired q-tiles, XCD-local bh)
  attn_kernel<<<dim3(512), blk, 0, stream>>>(qkvb, vTb, ctxb);
  // O-proj + residual -> d_out f32
  gemm_n128<1, false><<<dim3(16, 16), blk512, 0, stream>>>(
      ctxb, 2048, woT, nullptr, bo, nullptr, hs, d_out, 2048, 2048);
  ln_kernel<<<dim3(4096), blk, 0, stream>>>(outf, ln2g, ln2b, hbuf);
  // fused MLP gate/up: out = (h2@wfc + bfc) * silu(h2@wfc2 + bfc2)
  gemm_mlp<<<dim3(48, 16), blk512, 0, stream>>>(
      hbuf, 2048, wfcT, wfc2T, bfc, bfc2, qkvb, 6144, 2048);
  // proj + residual -> d_out
  gemm_n128<1, false><<<dim3(16, 16), blk512, 0, stream>>>(
      qkvb, 6144, wpjT, nullptr, bpj, nullptr, outf, d_out, 2048, 6144);
}